// Round 7
// baseline (590.485 us; speedup 1.0000x reference)
//
#include <hip/hip_runtime.h>

#define NB 4
#define SEQ 1024
#define DM 1024
#define NH 16
#define DEP 64
#define DFFN 4096

typedef __attribute__((ext_vector_type(8))) short short8;
typedef __attribute__((ext_vector_type(4))) float f32x4;
typedef __attribute__((ext_vector_type(4))) unsigned short us4;

__device__ __forceinline__ unsigned short f2bf(float f) {
    union { float f; unsigned int u; } v; v.f = f;
    unsigned int u = v.u;
    return (unsigned short)((u + 0x7FFFu + ((u >> 16) & 1u)) >> 16);
}

__device__ __forceinline__ void gload16(const void* g, void* l) {
    __builtin_amdgcn_global_load_lds((const __attribute__((address_space(1))) unsigned int*)g,
                                     (__attribute__((address_space(3))) unsigned int*)l, 16, 0, 0);
}

// ---------------- dual cast f32 -> bf16 ----------------
__global__ __launch_bounds__(256) void cast2_kernel(const float* __restrict__ a,
                                                    const float* __restrict__ b,
                                                    unsigned short* __restrict__ oa,
                                                    unsigned short* __restrict__ ob, int n4) {
    int i = blockIdx.x * 256 + threadIdx.x;
    const float* in = blockIdx.y ? b : a;
    unsigned short* out = blockIdx.y ? ob : oa;
    if (i < n4) {
        float4 f = ((const float4*)in)[i];
        us4 u;
        u[0] = f2bf(f.x); u[1] = f2bf(f.y); u[2] = f2bf(f.z); u[3] = f2bf(f.w);
        ((us4*)out)[i] = u;
    }
}

// ---------------- batched transpose-cast: 8 squares + wf1 + wf2, one launch ----------------
struct P10 { const float* p[10]; };
__global__ __launch_bounds__(256) void castTall_kernel(P10 s,
                                                       unsigned short* __restrict__ wsq,
                                                       unsigned short* __restrict__ wf1t,
                                                       unsigned short* __restrict__ wf2t) {
    __shared__ float tile[64][65];
    const int tid = blockIdx.x, t = threadIdx.x;
    const float* in; unsigned short* out; int R, C, r0, c0;
    if (tid < 2048) {
        int wi = tid >> 8, t2 = tid & 255;
        in = s.p[wi]; out = wsq + (size_t)wi * DM * DM; R = DM; C = DM;
        r0 = (t2 >> 4) * 64; c0 = (t2 & 15) * 64;
    } else if (tid < 3072) {
        int t2 = tid - 2048;
        in = s.p[8]; out = wf1t; R = DM; C = DFFN;
        r0 = (t2 >> 6) * 64; c0 = (t2 & 63) * 64;
    } else {
        int t2 = tid - 3072;
        in = s.p[9]; out = wf2t; R = DFFN; C = DM;
        r0 = (t2 >> 4) * 64; c0 = (t2 & 15) * 64;
    }
#pragma unroll
    for (int p = 0; p < 4; ++p) {
        int r = p * 16 + (t >> 4), c = (t & 15) * 4;
        float4 f = *(const float4*)(in + (size_t)(r0 + r) * C + c0 + c);
        tile[r][c] = f.x; tile[r][c + 1] = f.y; tile[r][c + 2] = f.z; tile[r][c + 3] = f.w;
    }
    __syncthreads();
#pragma unroll
    for (int p = 0; p < 4; ++p) {
        int n = p * 16 + (t >> 4), k = (t & 15) * 4;
        us4 u;
#pragma unroll
        for (int j = 0; j < 4; ++j) u[j] = f2bf(tile[k + j][n]);
        *(us4*)(out + (size_t)(c0 + n) * R + r0 + k) = u;
    }
}

// ---------------- bias concat pack ----------------
__global__ __launch_bounds__(256) void biaspack_kernel(const float* __restrict__ bq1,
                                                       const float* __restrict__ bk1,
                                                       const float* __restrict__ bv1,
                                                       const float* __restrict__ bk2,
                                                       const float* __restrict__ bv2,
                                                       float* __restrict__ bqkv1,
                                                       float* __restrict__ bkv2) {
    int i = blockIdx.x * 256 + threadIdx.x;
    if (i < 1024) bqkv1[i] = bq1[i];
    else if (i < 2048) bqkv1[i] = bk1[i - 1024];
    else if (i < 3072) bqkv1[i] = bv1[i - 2048];
    else if (i < 4096) bkv2[i - 3072] = bk2[i - 3072];
    else if (i < 5120) bkv2[i - 3072] = bv2[i - 4096];
}

// ---------------- m97-style bf16 GEMM: C = A(MxK) @ Wt^T + bias ----------------
template <int BM, int BN, int BK, int KSPLIT, int RELU, int WB, int WF, int WVT>
__global__ __launch_bounds__(256) void gemm_kernel(const unsigned short* __restrict__ A,
                                                   const unsigned short* __restrict__ Wt,
                                                   const float* __restrict__ bias,
                                                   unsigned short* __restrict__ Cb,
                                                   float* __restrict__ Cf,
                                                   float* __restrict__ Cf2,
                                                   unsigned short* __restrict__ Vt,
                                                   int vstart,
                                                   int M, int N, int K) {
    constexpr int AM = BM / 32;
    constexpr int KS = BK / 32;
    constexpr int LPR = BK / 8;
    constexpr int RPI = 64 / LPR;
    constexpr int AR = (BM / 4) / RPI;
    constexpr int BR = (BN / 4) / RPI;
    __shared__ unsigned short As[BM * BK];
    __shared__ unsigned short Bs[BN * BK];
    const int t = threadIdx.x;
    const int lane = t & 63, w = t >> 6;
    const int m0 = blockIdx.y * BM, n0 = blockIdx.x * BN;
    const int wm = (w >> 1) * (BM / 2), wn = (w & 1) * (BN / 2);
    const int lr = lane & 15, g = lane >> 4, kb = g * 8;
    const int srow = lane / LPR, scol = (lane % LPR) * 8;
    const int kofs = (KSPLIT == 2 && blockIdx.z) ? K / 2 : 0;
    const int Keff = (KSPLIT == 2) ? K / 2 : K;

    f32x4 acc[AM][4];
#pragma unroll
    for (int a = 0; a < AM; ++a)
#pragma unroll
        for (int b = 0; b < 4; ++b)
#pragma unroll
            for (int j = 0; j < 4; ++j) acc[a][b][j] = 0.f;

    for (int kt = 0; kt < Keff; kt += BK) {
        __syncthreads();
#pragma unroll
        for (int ia = 0; ia < AR; ++ia) {
            int rb = w * (BM / 4) + ia * RPI;
            gload16(A + (size_t)(m0 + rb + srow) * K + kofs + kt + scol, As + rb * BK);
        }
#pragma unroll
        for (int ib = 0; ib < BR; ++ib) {
            int rb = w * (BN / 4) + ib * RPI;
            gload16(Wt + (size_t)(n0 + rb + srow) * K + kofs + kt + scol, Bs + rb * BK);
        }
        __syncthreads();

        short8 af[AM][KS], bfr[4][KS];
#pragma unroll
        for (int i = 0; i < AM; ++i)
#pragma unroll
            for (int ks = 0; ks < KS; ++ks)
                af[i][ks] = *(const short8*)&As[(wm + i * 16 + lr) * BK + ks * 32 + kb];
#pragma unroll
        for (int i = 0; i < 4; ++i)
#pragma unroll
            for (int ks = 0; ks < KS; ++ks)
                bfr[i][ks] = *(const short8*)&Bs[(wn + i * 16 + lr) * BK + ks * 32 + kb];
#pragma unroll
        for (int ks = 0; ks < KS; ++ks)
#pragma unroll
            for (int am = 0; am < AM; ++am)
#pragma unroll
                for (int bn = 0; bn < 4; ++bn)
                    acc[am][bn] = __builtin_amdgcn_mfma_f32_16x16x32_bf16(af[am][ks], bfr[bn][ks], acc[am][bn], 0, 0, 0);
    }

    float* cfo = (KSPLIT == 2 && blockIdx.z) ? Cf2 : Cf;
    const bool addb = bias && (KSPLIT == 1 || blockIdx.z == 0);
#pragma unroll
    for (int am = 0; am < AM; ++am) {
#pragma unroll
        for (int bn = 0; bn < 4; ++bn) {
            int col = n0 + wn + bn * 16 + lr;
            float bv = addb ? bias[col] : 0.f;
            int rowb = m0 + wm + am * 16 + g * 4;
            float vv[4];
#pragma unroll
            for (int i = 0; i < 4; ++i) {
                float v = acc[am][bn][i] + bv;
                if (RELU) v = v > 0.f ? v : 0.f;
                vv[i] = v;
                if (WF) cfo[(size_t)(rowb + i) * N + col] = v;
                if (WB) Cb[(size_t)(rowb + i) * N + col] = f2bf(v);
            }
            if (WVT && col >= vstart) {
                int h = (col - vstart) >> 6, dep = (col - vstart) & 63;
                int b = rowb >> 10, kpos = rowb & 1023;
                us4 u;
#pragma unroll
                for (int i = 0; i < 4; ++i) u[i] = f2bf(vv[i]);
                *(us4*)(Vt + ((size_t)(b * NH + h) * DEP + dep) * SEQ + kpos) = u;
            }
        }
    }
}

// ---------------- fused attention v4: dbuf-prefetched K (128-row chunks), swapped QK^T ----------------
// grid 2048: bh = (id&7) + ((id>>8)<<3), qt = (id>>3)&31, q0 = qt*32.
// Lane holds S^T: q = q0 + p*16 + lr, k = c*128 + w*32 + bn*16 + g*4 + i.
template <int CAUSAL>
__global__ __launch_bounds__(256, 2) void attn_kernel(const unsigned short* __restrict__ Q, int ldq,
                                                      const unsigned short* __restrict__ Kp, int ldk,
                                                      const unsigned short* __restrict__ Vt,
                                                      const float* __restrict__ pad,
                                                      float* __restrict__ aw,
                                                      unsigned short* __restrict__ ctx) {
    __shared__ unsigned short Ks[2][128 * 64];  // 2 x 16 KB dbuf, source-swizzled
    __shared__ unsigned short Pch[32 * 128];    // 8 KB, 16B-XOR swizzled
    __shared__ float redm[4][32];
    __shared__ float reds[4][32];
    const int t = threadIdx.x, lane = t & 63, w = t >> 6;
    const int lr = lane & 15, g = lane >> 4;
    const int id = blockIdx.x;
    const int bh = (id & 7) + ((id >> 8) << 3);
    const int qt = (id >> 3) & 31;
    const int q0 = qt * 32;
    const int b = bh >> 4, h = bh & 15;
    const size_t qbase = (size_t)b * SEQ * ldq + (size_t)h * DEP;
    const size_t kbase = (size_t)b * SEQ * ldk + (size_t)h * DEP;
    const int cmax = CAUSAL ? (q0 >> 7) + 1 : 8;

    // staging decomposition: 8 rows x 8 slots(16B); source slot pre-swizzled (involution with read XOR)
    const int srow = lane >> 3;
    const int sslot = (lane & 7) ^ srow;

    // Q fragments: row q0 + p*16 + lr, depth ks*32 + g*8
    short8 aq[2][2];
#pragma unroll
    for (int p = 0; p < 2; ++p)
#pragma unroll
        for (int ks = 0; ks < 2; ++ks)
            aq[p][ks] = *(const short8*)(Q + qbase + (size_t)(q0 + p * 16 + lr) * ldq + ks * 32 + g * 8);

    f32x4 acc[2][8][2];
#pragma unroll
    for (int p = 0; p < 2; ++p)
#pragma unroll
        for (int c = 0; c < 8; ++c)
#pragma unroll
            for (int bn = 0; bn < 2; ++bn)
#pragma unroll
                for (int j = 0; j < 4; ++j) acc[p][c][bn][j] = 0.f;

    // ---- QK^T with prefetch: stage chunk c+1 while computing chunk c ----
    {
        // prologue: stage chunk 0 into buf 0 (wave w stages rows [w*32, w*32+32))
#pragma unroll
        for (int i = 0; i < 4; ++i) {
            int rb = w * 32 + i * 8;
            gload16(Kp + kbase + (size_t)(0 * 128 + rb + srow) * ldk + sslot * 8, &Ks[0][rb * 64]);
        }
    }
#pragma unroll
    for (int c = 0; c < 8; ++c) {
        if (c < cmax) {
            __syncthreads();  // drains vmcnt -> Ks[c&1] ready
            if (c + 1 < cmax) {
#pragma unroll
                for (int i = 0; i < 4; ++i) {
                    int rb = w * 32 + i * 8;
                    gload16(Kp + kbase + (size_t)((c + 1) * 128 + rb + srow) * ldk + sslot * 8,
                            &Ks[(c + 1) & 1][rb * 64]);
                }
            }
#pragma unroll
            for (int ks = 0; ks < 2; ++ks)
#pragma unroll
                for (int bn = 0; bn < 2; ++bn) {
                    int row = w * 32 + bn * 16 + lr;
                    short8 bk = *(const short8*)((const char*)&Ks[c & 1][0] + row * 128 +
                                                 ((ks * 64 + g * 16) ^ ((lr & 7) << 4)));
                    acc[0][c][bn] = __builtin_amdgcn_mfma_f32_16x16x32_bf16(bk, aq[0][ks], acc[0][c][bn], 0, 0, 0);
                    acc[1][c][bn] = __builtin_amdgcn_mfma_f32_16x16x32_bf16(bk, aq[1][ks], acc[1][c][bn], 0, 0, 0);
                }
        }
    }

    // ---- scale + masks + row max ----
    float mrow[2] = {-1e30f, -1e30f};
#pragma unroll
    for (int c = 0; c < 8; ++c) {
        if (c < cmax) {
#pragma unroll
            for (int bn = 0; bn < 2; ++bn) {
                int k4 = c * 128 + w * 32 + bn * 16 + g * 4;
                f32x4 pv = {0.f, 0.f, 0.f, 0.f};
                if (pad) pv = *(const f32x4*)(pad + (size_t)b * SEQ + k4);
#pragma unroll
                for (int p = 0; p < 2; ++p) {
                    int q = q0 + p * 16 + lr;
#pragma unroll
                    for (int i = 0; i < 4; ++i) {
                        float v = acc[p][c][bn][i] * 0.125f + pv[i] * -1e9f;
                        if (CAUSAL && (k4 + i) > q) v = -1e30f;
                        acc[p][c][bn][i] = v;
                        mrow[p] = fmaxf(mrow[p], v);
                    }
                }
            }
        }
    }
#pragma unroll
    for (int p = 0; p < 2; ++p) {
        mrow[p] = fmaxf(mrow[p], __shfl_xor(mrow[p], 16));
        mrow[p] = fmaxf(mrow[p], __shfl_xor(mrow[p], 32));
    }
    if (lane < 16) { redm[w][lr] = mrow[0]; redm[w][16 + lr] = mrow[1]; }
    __syncthreads();
    float Mv[2];
#pragma unroll
    for (int p = 0; p < 2; ++p)
        Mv[p] = fmaxf(fmaxf(redm[0][p * 16 + lr], redm[1][p * 16 + lr]),
                      fmaxf(redm[2][p * 16 + lr], redm[3][p * 16 + lr]));

    // ---- exp + row sum ----
    float srw[2] = {0.f, 0.f};
#pragma unroll
    for (int c = 0; c < 8; ++c) {
        if (c < cmax) {
#pragma unroll
            for (int p = 0; p < 2; ++p)
#pragma unroll
                for (int bn = 0; bn < 2; ++bn)
#pragma unroll
                    for (int i = 0; i < 4; ++i) {
                        float e = __expf(acc[p][c][bn][i] - Mv[p]);
                        acc[p][c][bn][i] = e;
                        srw[p] += e;
                    }
        }
    }
#pragma unroll
    for (int p = 0; p < 2; ++p) {
        srw[p] += __shfl_xor(srw[p], 16);
        srw[p] += __shfl_xor(srw[p], 32);
    }
    if (lane < 16) { reds[w][lr] = srw[0]; reds[w][16 + lr] = srw[1]; }
    __syncthreads();
    float inv[2];
#pragma unroll
    for (int p = 0; p < 2; ++p)
        inv[p] = 1.0f / (reds[0][p * 16 + lr] + reds[1][p * 16 + lr] +
                         reds[2][p * 16 + lr] + reds[3][p * 16 + lr]);

    // ---- aw writes: float4 per (p,c,bn), zero-fill beyond cmax ----
#pragma unroll
    for (int p = 0; p < 2; ++p) {
        float* awrow = aw + ((size_t)bh * SEQ + q0 + p * 16 + lr) * SEQ;
#pragma unroll
        for (int c = 0; c < 8; ++c)
#pragma unroll
            for (int bn = 0; bn < 2; ++bn) {
                f32x4 o = {0.f, 0.f, 0.f, 0.f};
                if (c < cmax) {
#pragma unroll
                    for (int i = 0; i < 4; ++i) o[i] = acc[p][c][bn][i] * inv[p];
                }
                *(f32x4*)(awrow + c * 128 + w * 32 + bn * 16 + g * 4) = o;
            }
    }

    // ---- PV: per-chunk P in swizzled LDS (rows 32 x 128 k, 256B rows); wave w owns d-tile w*16 ----
    f32x4 acc2[2];
#pragma unroll
    for (int p = 0; p < 2; ++p)
#pragma unroll
        for (int j = 0; j < 4; ++j) acc2[p][j] = 0.f;
    char* pch = (char*)Pch;
    const int sw = (lr & 7) << 4;
#pragma unroll
    for (int c = 0; c < 8; ++c) {
        if (c < cmax) {
            __syncthreads();
#pragma unroll
            for (int p = 0; p < 2; ++p)
#pragma unroll
                for (int bn = 0; bn < 2; ++bn) {
                    us4 u;
#pragma unroll
                    for (int i = 0; i < 4; ++i) u[i] = f2bf(acc[p][c][bn][i] * inv[p]);
                    *(us4*)(pch + (p * 16 + lr) * 256 + ((w * 64 + bn * 32 + g * 8) ^ sw)) = u;
                }
            __syncthreads();
#pragma unroll
            for (int ks = 0; ks < 4; ++ks) {
                short8 bf = *(const short8*)(Vt + ((size_t)bh * DEP + w * 16 + lr) * SEQ + c * 128 + ks * 32 + g * 8);
#pragma unroll
                for (int p = 0; p < 2; ++p) {
                    short8 af = *(const short8*)(pch + (p * 16 + lr) * 256 + ((ks * 64 + g * 16) ^ sw));
                    acc2[p] = __builtin_amdgcn_mfma_f32_16x16x32_bf16(af, bf, acc2[p], 0, 0, 0);
                }
            }
        }
    }
#pragma unroll
    for (int p = 0; p < 2; ++p)
#pragma unroll
        for (int i = 0; i < 4; ++i)
            ctx[((size_t)b * SEQ + q0 + p * 16 + g * 4 + i) * DM + h * DEP + w * 16 + lr] = f2bf(acc2[p][i]);
}

// ---------------- residual + layernorm: out = LN(X [+ X2] + R) ----------------
template <int WB, int X2EN>
__global__ __launch_bounds__(256) void ln_kernel(const float* __restrict__ X,
                                                 const float* __restrict__ X2,
                                                 const float* __restrict__ R,
                                                 const float* __restrict__ gamma,
                                                 const float* __restrict__ beta,
                                                 float* __restrict__ outF,
                                                 unsigned short* __restrict__ outB) {
    size_t row = blockIdx.x;
    const int t = threadIdx.x;
    float4 a = ((const float4*)(X + (row << 10)))[t];
    float4 r = ((const float4*)(R + (row << 10)))[t];
    float v0 = a.x + r.x, v1 = a.y + r.y, v2 = a.z + r.z, v3 = a.w + r.w;
    if (X2EN) {
        float4 a2 = ((const float4*)(X2 + (row << 10)))[t];
        v0 += a2.x; v1 += a2.y; v2 += a2.z; v3 += a2.w;
    }
    float s = v0 + v1 + v2 + v3;
    float q = v0 * v0 + v1 * v1 + v2 * v2 + v3 * v3;
#pragma unroll
    for (int off = 32; off; off >>= 1) {
        s += __shfl_down(s, off);
        q += __shfl_down(q, off);
    }
    __shared__ float rs[4], rq[4];
    if ((t & 63) == 0) { rs[t >> 6] = s; rq[t >> 6] = q; }
    __syncthreads();
    s = rs[0] + rs[1] + rs[2] + rs[3];
    q = rq[0] + rq[1] + rq[2] + rq[3];
    float mean = s * (1.0f / 1024.0f);
    float var = q * (1.0f / 1024.0f) - mean * mean;
    float inv = rsqrtf(var + 1e-6f);
    float g0 = gamma[t * 4], g1 = gamma[t * 4 + 1], g2 = gamma[t * 4 + 2], g3 = gamma[t * 4 + 3];
    float b0 = beta[t * 4], b1 = beta[t * 4 + 1], b2 = beta[t * 4 + 2], b3 = beta[t * 4 + 3];
    float o0 = (v0 - mean) * inv * g0 + b0;
    float o1 = (v1 - mean) * inv * g1 + b1;
    float o2 = (v2 - mean) * inv * g2 + b2;
    float o3 = (v3 - mean) * inv * g3 + b3;
    float4 o; o.x = o0; o.y = o1; o.z = o2; o.w = o3;
    ((float4*)(outF + (row << 10)))[t] = o;
    if (WB) {
        us4 u;
        u[0] = f2bf(o0); u[1] = f2bf(o1); u[2] = f2bf(o2); u[3] = f2bf(o3);
        ((us4*)(outB + (row << 10)))[t] = u;
    }
}

extern "C" void kernel_launch(void* const* d_in, const int* in_sizes, int n_in,
                              void* d_out, int out_size, void* d_ws, size_t ws_size,
                              hipStream_t stream) {
    const float* x = (const float*)d_in[0];
    const float* enc = (const float*)d_in[1];
    const float* pad = (const float*)d_in[3];
    const float* wq1 = (const float*)d_in[4];  const float* bq1 = (const float*)d_in[5];
    const float* wk1 = (const float*)d_in[6];  const float* bk1 = (const float*)d_in[7];
    const float* wv1 = (const float*)d_in[8];  const float* bv1 = (const float*)d_in[9];
    const float* wo1 = (const float*)d_in[10]; const float* bo1 = (const float*)d_in[11];
    const float* wq2 = (const float*)d_in[12]; const float* bq2 = (const float*)d_in[13];
    const float* wk2 = (const float*)d_in[14]; const float* bk2 = (const float*)d_in[15];
    const float* wv2 = (const float*)d_in[16]; const float* bv2 = (const float*)d_in[17];
    const float* wo2 = (const float*)d_in[18]; const float* bo2 = (const float*)d_in[19];
    const float* wf1 = (const float*)d_in[20]; const float* bf1 = (const float*)d_in[21];
    const float* wf2 = (const float*)d_in[22]; const float* bf2 = (const float*)d_in[23];
    const float* g1 = (const float*)d_in[24]; const float* be1 = (const float*)d_in[25];
    const float* g2 = (const float*)d_in[26]; const float* be2 = (const float*)d_in[27];
    const float* g3 = (const float*)d_in[28]; const float* be3 = (const float*)d_in[29];

    float* out3 = (float*)d_out;
    float* aw1 = out3 + (size_t)NB * SEQ * DM;
    float* aw2 = aw1 + (size_t)NB * NH * SEQ * SEQ;

    char* ws = (char*)d_ws;
    size_t off = 0;
    auto take = [&](size_t n) { char* p = ws + off; off += (n + 255) & ~(size_t)255; return p; };
    const size_t SZ_SD_BF = (size_t)NB * SEQ * DM * 2;
    const size_t SZ_SD_F  = (size_t)NB * SEQ * DM * 4;
    const size_t SZ_DD_BF = (size_t)DM * DM * 2;

    // 8 square transposed weights contiguous in this order (castTall indexes off wqkv1t):
    unsigned short* wqkv1t = (unsigned short*)take(3 * SZ_DD_BF);  // wq1,wk1,wv1
    unsigned short* wq2t   = (unsigned short*)take(SZ_DD_BF);
    unsigned short* wkv2t  = (unsigned short*)take(2 * SZ_DD_BF);  // wk2,wv2
    unsigned short* wo1t   = (unsigned short*)take(SZ_DD_BF);
    unsigned short* wo2t   = (unsigned short*)take(SZ_DD_BF);
    unsigned short* wf1t   = (unsigned short*)take((size_t)DM * DFFN * 2);
    unsigned short* wf2t   = (unsigned short*)take((size_t)DFFN * DM * 2);
    float* bqkv1 = (float*)take(3 * DM * 4);
    float* bkv2  = (float*)take(2 * DM * 4);
    unsigned short* xb    = (unsigned short*)take(SZ_SD_BF);
    unsigned short* encb  = (unsigned short*)take(SZ_SD_BF);
    unsigned short* qkv1b = (unsigned short*)take(3 * SZ_SD_BF);
    unsigned short* v1t   = (unsigned short*)take(SZ_SD_BF);
    unsigned short* qb    = (unsigned short*)take(SZ_SD_BF);
    unsigned short* kv2b  = (unsigned short*)take(2 * SZ_SD_BF);
    unsigned short* v2t   = (unsigned short*)take(SZ_SD_BF);
    unsigned short* ctx   = (unsigned short*)take(SZ_SD_BF);
    float* goutf  = (float*)take(SZ_SD_F);
    float* gout2f = (float*)take(SZ_SD_F);
    float* out1f  = (float*)take(SZ_SD_F);
    unsigned short* out1b = (unsigned short*)take(SZ_SD_BF);
    float* out2f  = (float*)take(SZ_SD_F);
    unsigned short* out2b = (unsigned short*)take(SZ_SD_BF);
    unsigned short* ffn1b = (unsigned short*)take((size_t)NB * SEQ * DFFN * 2);

    // ----- prep: 3 launches -----
    {
        int n4 = NB * SEQ * DM / 4;
        dim3 gc((n4 + 255) / 256, 2);
        cast2_kernel<<<gc, 256, 0, stream>>>(x, enc, xb, encb, n4);
    }
    {
        P10 s;
        s.p[0] = wq1; s.p[1] = wk1; s.p[2] = wv1; s.p[3] = wq2;
        s.p[4] = wk2; s.p[5] = wv2; s.p[6] = wo1; s.p[7] = wo2;
        s.p[8] = wf1; s.p[9] = wf2;
        castTall_kernel<<<4096, 256, 0, stream>>>(s, wqkv1t, wf1t, wf2t);
    }
    biaspack_kernel<<<20, 256, 0, stream>>>(bq1, bk1, bv1, bk2, bv2, bqkv1, bkv2);

    const int M = NB * SEQ;
    dim3 gQKV(3 * DM / 128, M / 128);
    dim3 gKV(2 * DM / 128, M / 128);
    dim3 gDD64(DM / 128, M / 64);
    dim3 gDF(DFFN / 128, M / 128);
    dim3 gF2(DM / 128, M / 128, 2);

    // ---- MHA1 (self, causal) ----
    gemm_kernel<128, 128, 64, 1, 0, 1, 0, 1><<<gQKV, 256, 0, stream>>>(xb, wqkv1t, bqkv1, qkv1b, nullptr, nullptr, v1t, 2048, M, 3 * DM, DM);
    attn_kernel<1><<<2048, 256, 0, stream>>>(qkv1b, 3 * DM, qkv1b + DM, 3 * DM, v1t, nullptr, aw1, ctx);
    gemm_kernel<64, 128, 64, 1, 0, 0, 1, 0><<<gDD64, 256, 0, stream>>>(ctx, wo1t, bo1, nullptr, goutf, nullptr, nullptr, 0, M, DM, DM);
    ln_kernel<1, 0><<<M, 256, 0, stream>>>(goutf, nullptr, x, g1, be1, out1f, out1b);

    // ---- MHA2 (cross, padding mask) ----
    gemm_kernel<64, 128, 64, 1, 0, 1, 0, 0><<<gDD64, 256, 0, stream>>>(out1b, wq2t, bq2, qb, nullptr, nullptr, nullptr, 0, M, DM, DM);
    gemm_kernel<128, 128, 64, 1, 0, 1, 0, 1><<<gKV, 256, 0, stream>>>(encb, wkv2t, bkv2, kv2b, nullptr, nullptr, v2t, 1024, M, 2 * DM, DM);
    attn_kernel<0><<<2048, 256, 0, stream>>>(qb, DM, kv2b, 2 * DM, v2t, pad, aw2, ctx);
    gemm_kernel<64, 128, 64, 1, 0, 0, 1, 0><<<gDD64, 256, 0, stream>>>(ctx, wo2t, bo2, nullptr, goutf, nullptr, nullptr, 0, M, DM, DM);
    ln_kernel<1, 0><<<M, 256, 0, stream>>>(goutf, nullptr, out1f, g2, be2, out2f, out2b);

    // ---- FFN ----
    gemm_kernel<128, 128, 64, 1, 1, 1, 0, 0><<<gDF, 256, 0, stream>>>(out2b, wf1t, bf1, ffn1b, nullptr, nullptr, nullptr, 0, M, DFFN, DM);
    gemm_kernel<128, 128, 64, 2, 0, 0, 1, 0><<<gF2, 256, 0, stream>>>(ffn1b, wf2t, bf2, nullptr, goutf, gout2f, nullptr, 0, M, DM, DFFN);
    ln_kernel<0, 1><<<M, 256, 0, stream>>>(goutf, gout2f, out2f, g3, be3, out3, nullptr);
}

// Round 8
// 577.694 us; speedup vs baseline: 1.0221x; 1.0221x over previous
//
#include <hip/hip_runtime.h>

#define NB 4
#define SEQ 1024
#define DM 1024
#define NH 16
#define DEP 64
#define DFFN 4096

typedef __attribute__((ext_vector_type(8))) short short8;
typedef __attribute__((ext_vector_type(4))) float f32x4;
typedef __attribute__((ext_vector_type(4))) unsigned short us4;

__device__ __forceinline__ unsigned short f2bf(float f) {
    union { float f; unsigned int u; } v; v.f = f;
    unsigned int u = v.u;
    return (unsigned short)((u + 0x7FFFu + ((u >> 16) & 1u)) >> 16);
}

__device__ __forceinline__ void gload16(const void* g, void* l) {
    __builtin_amdgcn_global_load_lds((const __attribute__((address_space(1))) unsigned int*)g,
                                     (__attribute__((address_space(3))) unsigned int*)l, 16, 0, 0);
}

// ---------------- dual cast f32 -> bf16 ----------------
__global__ __launch_bounds__(256) void cast2_kernel(const float* __restrict__ a,
                                                    const float* __restrict__ b,
                                                    unsigned short* __restrict__ oa,
                                                    unsigned short* __restrict__ ob, int n4) {
    int i = blockIdx.x * 256 + threadIdx.x;
    const float* in = blockIdx.y ? b : a;
    unsigned short* out = blockIdx.y ? ob : oa;
    if (i < n4) {
        float4 f = ((const float4*)in)[i];
        us4 u;
        u[0] = f2bf(f.x); u[1] = f2bf(f.y); u[2] = f2bf(f.z); u[3] = f2bf(f.w);
        ((us4*)out)[i] = u;
    }
}

// ---------------- batched transpose-cast: 8 squares + wf1 + wf2, one launch ----------------
struct P10 { const float* p[10]; };
__global__ __launch_bounds__(256) void castTall_kernel(P10 s,
                                                       unsigned short* __restrict__ wsq,
                                                       unsigned short* __restrict__ wf1t,
                                                       unsigned short* __restrict__ wf2t) {
    __shared__ float tile[64][65];
    const int tid = blockIdx.x, t = threadIdx.x;
    const float* in; unsigned short* out; int R, C, r0, c0;
    if (tid < 2048) {
        int wi = tid >> 8, t2 = tid & 255;
        in = s.p[wi]; out = wsq + (size_t)wi * DM * DM; R = DM; C = DM;
        r0 = (t2 >> 4) * 64; c0 = (t2 & 15) * 64;
    } else if (tid < 3072) {
        int t2 = tid - 2048;
        in = s.p[8]; out = wf1t; R = DM; C = DFFN;
        r0 = (t2 >> 6) * 64; c0 = (t2 & 63) * 64;
    } else {
        int t2 = tid - 3072;
        in = s.p[9]; out = wf2t; R = DFFN; C = DM;
        r0 = (t2 >> 4) * 64; c0 = (t2 & 15) * 64;
    }
#pragma unroll
    for (int p = 0; p < 4; ++p) {
        int r = p * 16 + (t >> 4), c = (t & 15) * 4;
        float4 f = *(const float4*)(in + (size_t)(r0 + r) * C + c0 + c);
        tile[r][c] = f.x; tile[r][c + 1] = f.y; tile[r][c + 2] = f.z; tile[r][c + 3] = f.w;
    }
    __syncthreads();
#pragma unroll
    for (int p = 0; p < 4; ++p) {
        int n = p * 16 + (t >> 4), k = (t & 15) * 4;
        us4 u;
#pragma unroll
        for (int j = 0; j < 4; ++j) u[j] = f2bf(tile[k + j][n]);
        *(us4*)(out + (size_t)(c0 + n) * R + r0 + k) = u;
    }
}

// ---------------- bias concat pack ----------------
__global__ __launch_bounds__(256) void biaspack_kernel(const float* __restrict__ bq1,
                                                       const float* __restrict__ bk1,
                                                       const float* __restrict__ bv1,
                                                       const float* __restrict__ bk2,
                                                       const float* __restrict__ bv2,
                                                       float* __restrict__ bqkv1,
                                                       float* __restrict__ bkv2) {
    int i = blockIdx.x * 256 + threadIdx.x;
    if (i < 1024) bqkv1[i] = bq1[i];
    else if (i < 2048) bqkv1[i] = bk1[i - 1024];
    else if (i < 3072) bqkv1[i] = bv1[i - 2048];
    else if (i < 4096) bkv2[i - 3072] = bk2[i - 3072];
    else if (i < 5120) bkv2[i - 3072] = bv2[i - 4096];
}

// ---------------- m97-style bf16 GEMM: C = A(MxK) @ Wt^T + bias ----------------
template <int BM, int BN, int BK, int KSPLIT, int RELU, int WB, int WF, int WVT>
__global__ __launch_bounds__(256) void gemm_kernel(const unsigned short* __restrict__ A,
                                                   const unsigned short* __restrict__ Wt,
                                                   const float* __restrict__ bias,
                                                   unsigned short* __restrict__ Cb,
                                                   float* __restrict__ Cf,
                                                   float* __restrict__ Cf2,
                                                   unsigned short* __restrict__ Vt,
                                                   int vstart,
                                                   int M, int N, int K) {
    constexpr int AM = BM / 32;
    constexpr int KS = BK / 32;
    constexpr int LPR = BK / 8;
    constexpr int RPI = 64 / LPR;
    constexpr int AR = (BM / 4) / RPI;
    constexpr int BR = (BN / 4) / RPI;
    __shared__ unsigned short As[BM * BK];
    __shared__ unsigned short Bs[BN * BK];
    const int t = threadIdx.x;
    const int lane = t & 63, w = t >> 6;
    const int m0 = blockIdx.y * BM, n0 = blockIdx.x * BN;
    const int wm = (w >> 1) * (BM / 2), wn = (w & 1) * (BN / 2);
    const int lr = lane & 15, g = lane >> 4, kb = g * 8;
    const int srow = lane / LPR, scol = (lane % LPR) * 8;
    const int kofs = (KSPLIT == 2 && blockIdx.z) ? K / 2 : 0;
    const int Keff = (KSPLIT == 2) ? K / 2 : K;

    f32x4 acc[AM][4];
#pragma unroll
    for (int a = 0; a < AM; ++a)
#pragma unroll
        for (int b = 0; b < 4; ++b)
#pragma unroll
            for (int j = 0; j < 4; ++j) acc[a][b][j] = 0.f;

    for (int kt = 0; kt < Keff; kt += BK) {
        __syncthreads();
#pragma unroll
        for (int ia = 0; ia < AR; ++ia) {
            int rb = w * (BM / 4) + ia * RPI;
            gload16(A + (size_t)(m0 + rb + srow) * K + kofs + kt + scol, As + rb * BK);
        }
#pragma unroll
        for (int ib = 0; ib < BR; ++ib) {
            int rb = w * (BN / 4) + ib * RPI;
            gload16(Wt + (size_t)(n0 + rb + srow) * K + kofs + kt + scol, Bs + rb * BK);
        }
        __syncthreads();

        short8 af[AM][KS], bfr[4][KS];
#pragma unroll
        for (int i = 0; i < AM; ++i)
#pragma unroll
            for (int ks = 0; ks < KS; ++ks)
                af[i][ks] = *(const short8*)&As[(wm + i * 16 + lr) * BK + ks * 32 + kb];
#pragma unroll
        for (int i = 0; i < 4; ++i)
#pragma unroll
            for (int ks = 0; ks < KS; ++ks)
                bfr[i][ks] = *(const short8*)&Bs[(wn + i * 16 + lr) * BK + ks * 32 + kb];
#pragma unroll
        for (int ks = 0; ks < KS; ++ks)
#pragma unroll
            for (int am = 0; am < AM; ++am)
#pragma unroll
                for (int bn = 0; bn < 4; ++bn)
                    acc[am][bn] = __builtin_amdgcn_mfma_f32_16x16x32_bf16(af[am][ks], bfr[bn][ks], acc[am][bn], 0, 0, 0);
    }

    float* cfo = (KSPLIT == 2 && blockIdx.z) ? Cf2 : Cf;
    const bool addb = bias && (KSPLIT == 1 || blockIdx.z == 0);
#pragma unroll
    for (int am = 0; am < AM; ++am) {
#pragma unroll
        for (int bn = 0; bn < 4; ++bn) {
            int col = n0 + wn + bn * 16 + lr;
            float bv = addb ? bias[col] : 0.f;
            int rowb = m0 + wm + am * 16 + g * 4;
            float vv[4];
#pragma unroll
            for (int i = 0; i < 4; ++i) {
                float v = acc[am][bn][i] + bv;
                if (RELU) v = v > 0.f ? v : 0.f;
                vv[i] = v;
                if (WF) cfo[(size_t)(rowb + i) * N + col] = v;
                if (WB) Cb[(size_t)(rowb + i) * N + col] = f2bf(v);
            }
            if (WVT && col >= vstart) {
                int h = (col - vstart) >> 6, dep = (col - vstart) & 63;
                int b = rowb >> 10, kpos = rowb & 1023;
                us4 u;
#pragma unroll
                for (int i = 0; i < 4; ++i) u[i] = f2bf(vv[i]);
                *(us4*)(Vt + ((size_t)(b * NH + h) * DEP + dep) * SEQ + kpos) = u;
            }
        }
    }
}

// ---------------- fused attention v5: dbuf K, swapped QK^T; aw stores issued LAST ----------------
// grid 2048: bh = (id&7) + ((id>>8)<<3), qt = (id>>3)&31, q0 = qt*32.
// Lane holds S^T: q = q0 + p*16 + lr, k = c*128 + w*32 + bn*16 + g*4 + i.
template <int CAUSAL>
__global__ __launch_bounds__(256, 2) void attn_kernel(const unsigned short* __restrict__ Q, int ldq,
                                                      const unsigned short* __restrict__ Kp, int ldk,
                                                      const unsigned short* __restrict__ Vt,
                                                      const float* __restrict__ pad,
                                                      float* __restrict__ aw,
                                                      unsigned short* __restrict__ ctx) {
    __shared__ unsigned short Ks[2][128 * 64];  // 2 x 16 KB dbuf, source-swizzled
    __shared__ unsigned short Pch[32 * 128];    // 8 KB, 16B-XOR swizzled
    __shared__ float redm[4][32];
    __shared__ float reds[4][32];
    const int t = threadIdx.x, lane = t & 63, w = t >> 6;
    const int lr = lane & 15, g = lane >> 4;
    const int id = blockIdx.x;
    const int bh = (id & 7) + ((id >> 8) << 3);
    const int qt = (id >> 3) & 31;
    const int q0 = qt * 32;
    const int b = bh >> 4, h = bh & 15;
    const size_t qbase = (size_t)b * SEQ * ldq + (size_t)h * DEP;
    const size_t kbase = (size_t)b * SEQ * ldk + (size_t)h * DEP;
    const int cmax = CAUSAL ? (q0 >> 7) + 1 : 8;

    const int srow = lane >> 3;
    const int sslot = (lane & 7) ^ srow;

    short8 aq[2][2];
#pragma unroll
    for (int p = 0; p < 2; ++p)
#pragma unroll
        for (int ks = 0; ks < 2; ++ks)
            aq[p][ks] = *(const short8*)(Q + qbase + (size_t)(q0 + p * 16 + lr) * ldq + ks * 32 + g * 8);

    f32x4 acc[2][8][2];
#pragma unroll
    for (int p = 0; p < 2; ++p)
#pragma unroll
        for (int c = 0; c < 8; ++c)
#pragma unroll
            for (int bn = 0; bn < 2; ++bn)
#pragma unroll
                for (int j = 0; j < 4; ++j) acc[p][c][bn][j] = 0.f;

    // ---- QK^T with prefetch ----
    {
#pragma unroll
        for (int i = 0; i < 4; ++i) {
            int rb = w * 32 + i * 8;
            gload16(Kp + kbase + (size_t)(rb + srow) * ldk + sslot * 8, &Ks[0][rb * 64]);
        }
    }
#pragma unroll
    for (int c = 0; c < 8; ++c) {
        if (c < cmax) {
            __syncthreads();
            if (c + 1 < cmax) {
#pragma unroll
                for (int i = 0; i < 4; ++i) {
                    int rb = w * 32 + i * 8;
                    gload16(Kp + kbase + (size_t)((c + 1) * 128 + rb + srow) * ldk + sslot * 8,
                            &Ks[(c + 1) & 1][rb * 64]);
                }
            }
#pragma unroll
            for (int ks = 0; ks < 2; ++ks)
#pragma unroll
                for (int bn = 0; bn < 2; ++bn) {
                    int row = w * 32 + bn * 16 + lr;
                    short8 bk = *(const short8*)((const char*)&Ks[c & 1][0] + row * 128 +
                                                 ((ks * 64 + g * 16) ^ ((lr & 7) << 4)));
                    acc[0][c][bn] = __builtin_amdgcn_mfma_f32_16x16x32_bf16(bk, aq[0][ks], acc[0][c][bn], 0, 0, 0);
                    acc[1][c][bn] = __builtin_amdgcn_mfma_f32_16x16x32_bf16(bk, aq[1][ks], acc[1][c][bn], 0, 0, 0);
                }
        }
    }

    // ---- scale + masks + row max ----
    float mrow[2] = {-1e30f, -1e30f};
#pragma unroll
    for (int c = 0; c < 8; ++c) {
        if (c < cmax) {
#pragma unroll
            for (int bn = 0; bn < 2; ++bn) {
                int k4 = c * 128 + w * 32 + bn * 16 + g * 4;
                f32x4 pv = {0.f, 0.f, 0.f, 0.f};
                if (pad) pv = *(const f32x4*)(pad + (size_t)b * SEQ + k4);
#pragma unroll
                for (int p = 0; p < 2; ++p) {
                    int q = q0 + p * 16 + lr;
#pragma unroll
                    for (int i = 0; i < 4; ++i) {
                        float v = acc[p][c][bn][i] * 0.125f + pv[i] * -1e9f;
                        if (CAUSAL && (k4 + i) > q) v = -1e30f;
                        acc[p][c][bn][i] = v;
                        mrow[p] = fmaxf(mrow[p], v);
                    }
                }
            }
        }
    }
#pragma unroll
    for (int p = 0; p < 2; ++p) {
        mrow[p] = fmaxf(mrow[p], __shfl_xor(mrow[p], 16));
        mrow[p] = fmaxf(mrow[p], __shfl_xor(mrow[p], 32));
    }
    if (lane < 16) { redm[w][lr] = mrow[0]; redm[w][16 + lr] = mrow[1]; }
    __syncthreads();
    float Mv[2];
#pragma unroll
    for (int p = 0; p < 2; ++p)
        Mv[p] = fmaxf(fmaxf(redm[0][p * 16 + lr], redm[1][p * 16 + lr]),
                      fmaxf(redm[2][p * 16 + lr], redm[3][p * 16 + lr]));

    // ---- exp + row sum ----
    float srw[2] = {0.f, 0.f};
#pragma unroll
    for (int c = 0; c < 8; ++c) {
        if (c < cmax) {
#pragma unroll
            for (int p = 0; p < 2; ++p)
#pragma unroll
                for (int bn = 0; bn < 2; ++bn)
#pragma unroll
                    for (int i = 0; i < 4; ++i) {
                        float e = __expf(acc[p][c][bn][i] - Mv[p]);
                        acc[p][c][bn][i] = e;
                        srw[p] += e;
                    }
        }
    }
#pragma unroll
    for (int p = 0; p < 2; ++p) {
        srw[p] += __shfl_xor(srw[p], 16);
        srw[p] += __shfl_xor(srw[p], 32);
    }
    if (lane < 16) { reds[w][lr] = srw[0]; reds[w][16 + lr] = srw[1]; }
    __syncthreads();
    float inv[2];
#pragma unroll
    for (int p = 0; p < 2; ++p)
        inv[p] = 1.0f / (reds[0][p * 16 + lr] + reds[1][p * 16 + lr] +
                         reds[2][p * 16 + lr] + reds[3][p * 16 + lr]);

    // ---- PV FIRST (no outstanding global stores -> cheap barriers) ----
    f32x4 acc2[2];
#pragma unroll
    for (int p = 0; p < 2; ++p)
#pragma unroll
        for (int j = 0; j < 4; ++j) acc2[p][j] = 0.f;
    char* pch = (char*)Pch;
    const int sw = (lr & 7) << 4;
#pragma unroll
    for (int c = 0; c < 8; ++c) {
        if (c < cmax) {
            __syncthreads();
#pragma unroll
            for (int p = 0; p < 2; ++p)
#pragma unroll
                for (int bn = 0; bn < 2; ++bn) {
                    us4 u;
#pragma unroll
                    for (int i = 0; i < 4; ++i) u[i] = f2bf(acc[p][c][bn][i] * inv[p]);
                    *(us4*)(pch + (p * 16 + lr) * 256 + ((w * 64 + bn * 32 + g * 8) ^ sw)) = u;
                }
            __syncthreads();
#pragma unroll
            for (int ks = 0; ks < 4; ++ks) {
                short8 bf = *(const short8*)(Vt + ((size_t)bh * DEP + w * 16 + lr) * SEQ + c * 128 + ks * 32 + g * 8);
#pragma unroll
                for (int p = 0; p < 2; ++p) {
                    short8 af = *(const short8*)(pch + (p * 16 + lr) * 256 + ((ks * 64 + g * 16) ^ sw));
                    acc2[p] = __builtin_amdgcn_mfma_f32_16x16x32_bf16(af, bf, acc2[p], 0, 0, 0);
                }
            }
        }
    }
#pragma unroll
    for (int p = 0; p < 2; ++p)
#pragma unroll
        for (int i = 0; i < 4; ++i)
            ctx[((size_t)b * SEQ + q0 + p * 16 + g * 4 + i) * DM + h * DEP + w * 16 + lr] = f2bf(acc2[p][i]);

    // ---- aw writes LAST: drain overlaps kernel tail, no barrier afterward ----
#pragma unroll
    for (int p = 0; p < 2; ++p) {
        float* awrow = aw + ((size_t)bh * SEQ + q0 + p * 16 + lr) * SEQ;
#pragma unroll
        for (int c = 0; c < 8; ++c)
#pragma unroll
            for (int bn = 0; bn < 2; ++bn) {
                f32x4 o = {0.f, 0.f, 0.f, 0.f};
                if (c < cmax) {
#pragma unroll
                    for (int i = 0; i < 4; ++i) o[i] = acc[p][c][bn][i] * inv[p];
                }
                *(f32x4*)(awrow + c * 128 + w * 32 + bn * 16 + g * 4) = o;
            }
    }
}

// ---------------- residual + layernorm: out = LN(X [+ X2] + R) ----------------
template <int WB, int X2EN>
__global__ __launch_bounds__(256) void ln_kernel(const float* __restrict__ X,
                                                 const float* __restrict__ X2,
                                                 const float* __restrict__ R,
                                                 const float* __restrict__ gamma,
                                                 const float* __restrict__ beta,
                                                 float* __restrict__ outF,
                                                 unsigned short* __restrict__ outB) {
    size_t row = blockIdx.x;
    const int t = threadIdx.x;
    float4 a = ((const float4*)(X + (row << 10)))[t];
    float4 r = ((const float4*)(R + (row << 10)))[t];
    float v0 = a.x + r.x, v1 = a.y + r.y, v2 = a.z + r.z, v3 = a.w + r.w;
    if (X2EN) {
        float4 a2 = ((const float4*)(X2 + (row << 10)))[t];
        v0 += a2.x; v1 += a2.y; v2 += a2.z; v3 += a2.w;
    }
    float s = v0 + v1 + v2 + v3;
    float q = v0 * v0 + v1 * v1 + v2 * v2 + v3 * v3;
#pragma unroll
    for (int off = 32; off; off >>= 1) {
        s += __shfl_down(s, off);
        q += __shfl_down(q, off);
    }
    __shared__ float rs[4], rq[4];
    if ((t & 63) == 0) { rs[t >> 6] = s; rq[t >> 6] = q; }
    __syncthreads();
    s = rs[0] + rs[1] + rs[2] + rs[3];
    q = rq[0] + rq[1] + rq[2] + rq[3];
    float mean = s * (1.0f / 1024.0f);
    float var = q * (1.0f / 1024.0f) - mean * mean;
    float inv = rsqrtf(var + 1e-6f);
    float g0 = gamma[t * 4], g1 = gamma[t * 4 + 1], g2 = gamma[t * 4 + 2], g3 = gamma[t * 4 + 3];
    float b0 = beta[t * 4], b1 = beta[t * 4 + 1], b2 = beta[t * 4 + 2], b3 = beta[t * 4 + 3];
    float o0 = (v0 - mean) * inv * g0 + b0;
    float o1 = (v1 - mean) * inv * g1 + b1;
    float o2 = (v2 - mean) * inv * g2 + b2;
    float o3 = (v3 - mean) * inv * g3 + b3;
    float4 o; o.x = o0; o.y = o1; o.z = o2; o.w = o3;
    ((float4*)(outF + (row << 10)))[t] = o;
    if (WB) {
        us4 u;
        u[0] = f2bf(o0); u[1] = f2bf(o1); u[2] = f2bf(o2); u[3] = f2bf(o3);
        ((us4*)(outB + (row << 10)))[t] = u;
    }
}

extern "C" void kernel_launch(void* const* d_in, const int* in_sizes, int n_in,
                              void* d_out, int out_size, void* d_ws, size_t ws_size,
                              hipStream_t stream) {
    const float* x = (const float*)d_in[0];
    const float* enc = (const float*)d_in[1];
    const float* pad = (const float*)d_in[3];
    const float* wq1 = (const float*)d_in[4];  const float* bq1 = (const float*)d_in[5];
    const float* wk1 = (const float*)d_in[6];  const float* bk1 = (const float*)d_in[7];
    const float* wv1 = (const float*)d_in[8];  const float* bv1 = (const float*)d_in[9];
    const float* wo1 = (const float*)d_in[10]; const float* bo1 = (const float*)d_in[11];
    const float* wq2 = (const float*)d_in[12]; const float* bq2 = (const float*)d_in[13];
    const float* wk2 = (const float*)d_in[14]; const float* bk2 = (const float*)d_in[15];
    const float* wv2 = (const float*)d_in[16]; const float* bv2 = (const float*)d_in[17];
    const float* wo2 = (const float*)d_in[18]; const float* bo2 = (const float*)d_in[19];
    const float* wf1 = (const float*)d_in[20]; const float* bf1 = (const float*)d_in[21];
    const float* wf2 = (const float*)d_in[22]; const float* bf2 = (const float*)d_in[23];
    const float* g1 = (const float*)d_in[24]; const float* be1 = (const float*)d_in[25];
    const float* g2 = (const float*)d_in[26]; const float* be2 = (const float*)d_in[27];
    const float* g3 = (const float*)d_in[28]; const float* be3 = (const float*)d_in[29];

    float* out3 = (float*)d_out;
    float* aw1 = out3 + (size_t)NB * SEQ * DM;
    float* aw2 = aw1 + (size_t)NB * NH * SEQ * SEQ;

    char* ws = (char*)d_ws;
    size_t off = 0;
    auto take = [&](size_t n) { char* p = ws + off; off += (n + 255) & ~(size_t)255; return p; };
    const size_t SZ_SD_BF = (size_t)NB * SEQ * DM * 2;
    const size_t SZ_SD_F  = (size_t)NB * SEQ * DM * 4;
    const size_t SZ_DD_BF = (size_t)DM * DM * 2;

    unsigned short* wqkv1t = (unsigned short*)take(3 * SZ_DD_BF);
    unsigned short* wq2t   = (unsigned short*)take(SZ_DD_BF);
    unsigned short* wkv2t  = (unsigned short*)take(2 * SZ_DD_BF);
    unsigned short* wo1t   = (unsigned short*)take(SZ_DD_BF);
    unsigned short* wo2t   = (unsigned short*)take(SZ_DD_BF);
    unsigned short* wf1t   = (unsigned short*)take((size_t)DM * DFFN * 2);
    unsigned short* wf2t   = (unsigned short*)take((size_t)DFFN * DM * 2);
    float* bqkv1 = (float*)take(3 * DM * 4);
    float* bkv2  = (float*)take(2 * DM * 4);
    unsigned short* xb    = (unsigned short*)take(SZ_SD_BF);
    unsigned short* encb  = (unsigned short*)take(SZ_SD_BF);
    unsigned short* qkv1b = (unsigned short*)take(3 * SZ_SD_BF);
    unsigned short* v1t   = (unsigned short*)take(SZ_SD_BF);
    unsigned short* qb    = (unsigned short*)take(SZ_SD_BF);
    unsigned short* kv2b  = (unsigned short*)take(2 * SZ_SD_BF);
    unsigned short* v2t   = (unsigned short*)take(SZ_SD_BF);
    unsigned short* ctx   = (unsigned short*)take(SZ_SD_BF);
    float* goutf  = (float*)take(SZ_SD_F);
    float* gout2f = (float*)take(SZ_SD_F);
    float* out1f  = (float*)take(SZ_SD_F);
    unsigned short* out1b = (unsigned short*)take(SZ_SD_BF);
    float* out2f  = (float*)take(SZ_SD_F);
    unsigned short* out2b = (unsigned short*)take(SZ_SD_BF);
    unsigned short* ffn1b = (unsigned short*)take((size_t)NB * SEQ * DFFN * 2);

    // ----- prep: 3 launches -----
    {
        int n4 = NB * SEQ * DM / 4;
        dim3 gc((n4 + 255) / 256, 2);
        cast2_kernel<<<gc, 256, 0, stream>>>(x, enc, xb, encb, n4);
    }
    {
        P10 s;
        s.p[0] = wq1; s.p[1] = wk1; s.p[2] = wv1; s.p[3] = wq2;
        s.p[4] = wk2; s.p[5] = wv2; s.p[6] = wo1; s.p[7] = wo2;
        s.p[8] = wf1; s.p[9] = wf2;
        castTall_kernel<<<4096, 256, 0, stream>>>(s, wqkv1t, wf1t, wf2t);
    }
    biaspack_kernel<<<20, 256, 0, stream>>>(bq1, bk1, bv1, bk2, bv2, bqkv1, bkv2);

    const int M = NB * SEQ;
    dim3 gQKV(3 * DM / 128, M / 128);
    dim3 gKV(2 * DM / 128, M / 128);
    dim3 gDD64(DM / 128, M / 64);
    dim3 gDF(DFFN / 128, M / 128);
    dim3 gF2(DM / 128, M / 128, 2);

    // ---- MHA1 (self, causal) ----
    gemm_kernel<128, 128, 32, 1, 0, 1, 0, 1><<<gQKV, 256, 0, stream>>>(xb, wqkv1t, bqkv1, qkv1b, nullptr, nullptr, v1t, 2048, M, 3 * DM, DM);
    attn_kernel<1><<<2048, 256, 0, stream>>>(qkv1b, 3 * DM, qkv1b + DM, 3 * DM, v1t, nullptr, aw1, ctx);
    gemm_kernel<64, 128, 64, 1, 0, 0, 1, 0><<<gDD64, 256, 0, stream>>>(ctx, wo1t, bo1, nullptr, goutf, nullptr, nullptr, 0, M, DM, DM);
    ln_kernel<1, 0><<<M, 256, 0, stream>>>(goutf, nullptr, x, g1, be1, out1f, out1b);

    // ---- MHA2 (cross, padding mask) ----
    gemm_kernel<64, 128, 64, 1, 0, 1, 0, 0><<<gDD64, 256, 0, stream>>>(out1b, wq2t, bq2, qb, nullptr, nullptr, nullptr, 0, M, DM, DM);
    gemm_kernel<128, 128, 32, 1, 0, 1, 0, 1><<<gKV, 256, 0, stream>>>(encb, wkv2t, bkv2, kv2b, nullptr, nullptr, v2t, 1024, M, 2 * DM, DM);
    attn_kernel<0><<<2048, 256, 0, stream>>>(qb, DM, kv2b, 2 * DM, v2t, pad, aw2, ctx);
    gemm_kernel<64, 128, 64, 1, 0, 0, 1, 0><<<gDD64, 256, 0, stream>>>(ctx, wo2t, bo2, nullptr, goutf, nullptr, nullptr, 0, M, DM, DM);
    ln_kernel<1, 0><<<M, 256, 0, stream>>>(goutf, nullptr, out1f, g2, be2, out2f, out2b);

    // ---- FFN ----
    gemm_kernel<128, 128, 32, 1, 1, 1, 0, 0><<<gDF, 256, 0, stream>>>(out2b, wf1t, bf1, ffn1b, nullptr, nullptr, nullptr, 0, M, DFFN, DM);
    gemm_kernel<128, 128, 32, 2, 0, 0, 1, 0><<<gF2, 256, 0, stream>>>(ffn1b, wf2t, bf2, nullptr, goutf, gout2f, nullptr, 0, M, DM, DFFN);
    ln_kernel<0, 1><<<M, 256, 0, stream>>>(goutf, gout2f, out2f, g3, be3, out3, nullptr);
}

// Round 9
// 505.185 us; speedup vs baseline: 1.1688x; 1.1435x over previous
//
#include <hip/hip_runtime.h>

#define NB 4
#define SEQ 1024
#define DM 1024
#define NH 16
#define DEP 64
#define DFFN 4096

typedef __attribute__((ext_vector_type(8))) short short8;
typedef __attribute__((ext_vector_type(4))) float f32x4;
typedef __attribute__((ext_vector_type(4))) unsigned short us4;

__device__ __forceinline__ unsigned short f2bf(float f) {
    union { float f; unsigned int u; } v; v.f = f;
    unsigned int u = v.u;
    return (unsigned short)((u + 0x7FFFu + ((u >> 16) & 1u)) >> 16);
}

__device__ __forceinline__ void gload16(const void* g, void* l) {
    __builtin_amdgcn_global_load_lds((const __attribute__((address_space(1))) unsigned int*)g,
                                     (__attribute__((address_space(3))) unsigned int*)l, 16, 0, 0);
}

// ---------------- dual cast f32 -> bf16 (NT loads: read-once f32) ----------------
__global__ __launch_bounds__(256) void cast2_kernel(const float* __restrict__ a,
                                                    const float* __restrict__ b,
                                                    unsigned short* __restrict__ oa,
                                                    unsigned short* __restrict__ ob, int n4) {
    int i = blockIdx.x * 256 + threadIdx.x;
    const float* in = blockIdx.y ? b : a;
    unsigned short* out = blockIdx.y ? ob : oa;
    if (i < n4) {
        f32x4 f = __builtin_nontemporal_load((const f32x4*)in + i);
        us4 u;
        u[0] = f2bf(f[0]); u[1] = f2bf(f[1]); u[2] = f2bf(f[2]); u[3] = f2bf(f[3]);
        ((us4*)out)[i] = u;
    }
}

// ---------------- batched transpose-cast: 8 squares + wf1 + wf2, one launch ----------------
struct P10 { const float* p[10]; };
__global__ __launch_bounds__(256) void castTall_kernel(P10 s,
                                                       unsigned short* __restrict__ wsq,
                                                       unsigned short* __restrict__ wf1t,
                                                       unsigned short* __restrict__ wf2t) {
    __shared__ float tile[64][65];
    const int tid = blockIdx.x, t = threadIdx.x;
    const float* in; unsigned short* out; int R, C, r0, c0;
    if (tid < 2048) {
        int wi = tid >> 8, t2 = tid & 255;
        in = s.p[wi]; out = wsq + (size_t)wi * DM * DM; R = DM; C = DM;
        r0 = (t2 >> 4) * 64; c0 = (t2 & 15) * 64;
    } else if (tid < 3072) {
        int t2 = tid - 2048;
        in = s.p[8]; out = wf1t; R = DM; C = DFFN;
        r0 = (t2 >> 6) * 64; c0 = (t2 & 63) * 64;
    } else {
        int t2 = tid - 3072;
        in = s.p[9]; out = wf2t; R = DFFN; C = DM;
        r0 = (t2 >> 4) * 64; c0 = (t2 & 15) * 64;
    }
#pragma unroll
    for (int p = 0; p < 4; ++p) {
        int r = p * 16 + (t >> 4), c = (t & 15) * 4;
        f32x4 f = __builtin_nontemporal_load((const f32x4*)(in + (size_t)(r0 + r) * C + c0 + c));
        tile[r][c] = f[0]; tile[r][c + 1] = f[1]; tile[r][c + 2] = f[2]; tile[r][c + 3] = f[3];
    }
    __syncthreads();
#pragma unroll
    for (int p = 0; p < 4; ++p) {
        int n = p * 16 + (t >> 4), k = (t & 15) * 4;
        us4 u;
#pragma unroll
        for (int j = 0; j < 4; ++j) u[j] = f2bf(tile[k + j][n]);
        *(us4*)(out + (size_t)(c0 + n) * R + r0 + k) = u;
    }
}

// ---------------- bias concat pack ----------------
__global__ __launch_bounds__(256) void biaspack_kernel(const float* __restrict__ bq1,
                                                       const float* __restrict__ bk1,
                                                       const float* __restrict__ bv1,
                                                       const float* __restrict__ bk2,
                                                       const float* __restrict__ bv2,
                                                       float* __restrict__ bqkv1,
                                                       float* __restrict__ bkv2) {
    int i = blockIdx.x * 256 + threadIdx.x;
    if (i < 1024) bqkv1[i] = bq1[i];
    else if (i < 2048) bqkv1[i] = bk1[i - 1024];
    else if (i < 3072) bqkv1[i] = bv1[i - 2048];
    else if (i < 4096) bkv2[i - 3072] = bk2[i - 3072];
    else if (i < 5120) bkv2[i - 3072] = bv2[i - 4096];
}

// ---------------- bf16 GEMM: dbuf LDS + counted vmcnt across raw barriers (T3/T4) ----------------
// A row-major [M][K]; Wt row-major [N][K]. XCD-chunked block swizzle (T1).
template <int BM, int BN, int BK, int KSPLIT, int RELU, int WB, int WF, int WVT>
__global__ __launch_bounds__(256) void gemm_kernel(const unsigned short* __restrict__ A,
                                                   const unsigned short* __restrict__ Wt,
                                                   const float* __restrict__ bias,
                                                   unsigned short* __restrict__ Cb,
                                                   float* __restrict__ Cf,
                                                   float* __restrict__ Cf2,
                                                   unsigned short* __restrict__ Vt,
                                                   int vstart,
                                                   int M, int N, int K) {
    constexpr int AM = BM / 32;
    constexpr int KS = BK / 32;
    constexpr int LPR = BK / 8;          // lanes per row-segment (16B each)
    constexpr int RPI = 64 / LPR;        // rows per gload issue
    constexpr int AR = (BM / 4) / RPI;   // A issues per wave
    constexpr int BR = (BN / 4) / RPI;
    constexpr int NLD = AR + BR;         // loads in flight per staged tile (per thread)
    __shared__ unsigned short As[2][BM * BK];
    __shared__ unsigned short Bs[2][BN * BK];
    const int t = threadIdx.x;
    const int lane = t & 63, w = t >> 6;
    // XCD-chunked bijective swizzle (all grids have nwg % 8 == 0)
    const int nwg = gridDim.x * gridDim.y;
    const int rawid = blockIdx.y * gridDim.x + blockIdx.x;
    const int swz = (rawid & 7) * (nwg >> 3) + (rawid >> 3);
    const int m0 = (swz / gridDim.x) * BM, n0 = (swz % gridDim.x) * BN;
    const int wm = (w >> 1) * (BM / 2), wn = (w & 1) * (BN / 2);
    const int lr = lane & 15, g = lane >> 4, kb = g * 8;
    const int srow = lane / LPR, scol = (lane % LPR) * 8;
    const int kofs = (KSPLIT == 2 && blockIdx.z) ? K / 2 : 0;
    const int Keff = (KSPLIT == 2) ? K / 2 : K;
    const int nk = Keff / BK;

    f32x4 acc[AM][4];
#pragma unroll
    for (int a = 0; a < AM; ++a)
#pragma unroll
        for (int b = 0; b < 4; ++b)
#pragma unroll
            for (int j = 0; j < 4; ++j) acc[a][b][j] = 0.f;

    auto STAGE = [&](int buf, int kt) {
#pragma unroll
        for (int ia = 0; ia < AR; ++ia) {
            int rb = w * (BM / 4) + ia * RPI;
            gload16(A + (size_t)(m0 + rb + srow) * K + kt + scol, &As[buf][rb * BK]);
        }
#pragma unroll
        for (int ib = 0; ib < BR; ++ib) {
            int rb = w * (BN / 4) + ib * RPI;
            gload16(Wt + (size_t)(n0 + rb + srow) * K + kt + scol, &Bs[buf][rb * BK]);
        }
    };

    STAGE(0, kofs);
    for (int i = 0; i < nk; ++i) {
        const int cur = i & 1;
        if (i + 1 < nk) {
            STAGE(cur ^ 1, kofs + (i + 1) * BK);
            // wait only for buf[cur]'s loads; next tile's NLD stay in flight across barriers
            asm volatile("s_waitcnt vmcnt(%0)" :: "n"(NLD) : "memory");
        } else {
            asm volatile("s_waitcnt vmcnt(0)" ::: "memory");
        }
        __builtin_amdgcn_s_barrier();   // all waves' buf[cur] loads retired

        short8 af[AM][KS], bfr[4][KS];
#pragma unroll
        for (int ii = 0; ii < AM; ++ii)
#pragma unroll
            for (int ks = 0; ks < KS; ++ks)
                af[ii][ks] = *(const short8*)&As[cur][(wm + ii * 16 + lr) * BK + ks * 32 + kb];
#pragma unroll
        for (int ii = 0; ii < 4; ++ii)
#pragma unroll
            for (int ks = 0; ks < KS; ++ks)
                bfr[ii][ks] = *(const short8*)&Bs[cur][(wn + ii * 16 + lr) * BK + ks * 32 + kb];
#pragma unroll
        for (int ks = 0; ks < KS; ++ks)
#pragma unroll
            for (int am = 0; am < AM; ++am)
#pragma unroll
                for (int bn = 0; bn < 4; ++bn)
                    acc[am][bn] = __builtin_amdgcn_mfma_f32_16x16x32_bf16(af[am][ks], bfr[bn][ks], acc[am][bn], 0, 0, 0);
        __builtin_amdgcn_s_barrier();   // reads retired (consumed by MFMAs) before buf[cur] is overwritten
    }

    float* cfo = (KSPLIT == 2 && blockIdx.z) ? Cf2 : Cf;
    const bool addb = bias && (KSPLIT == 1 || blockIdx.z == 0);
#pragma unroll
    for (int am = 0; am < AM; ++am) {
#pragma unroll
        for (int bn = 0; bn < 4; ++bn) {
            int col = n0 + wn + bn * 16 + lr;
            float bv = addb ? bias[col] : 0.f;
            int rowb = m0 + wm + am * 16 + g * 4;
            float vv[4];
#pragma unroll
            for (int i = 0; i < 4; ++i) {
                float v = acc[am][bn][i] + bv;
                if (RELU) v = v > 0.f ? v : 0.f;
                vv[i] = v;
                if (WF) cfo[(size_t)(rowb + i) * N + col] = v;
                if (WB) Cb[(size_t)(rowb + i) * N + col] = f2bf(v);
            }
            if (WVT && col >= vstart) {
                int h = (col - vstart) >> 6, dep = (col - vstart) & 63;
                int b = rowb >> 10, kpos = rowb & 1023;
                us4 u;
#pragma unroll
                for (int i = 0; i < 4; ++i) u[i] = f2bf(vv[i]);
                *(us4*)(Vt + ((size_t)(b * NH + h) * DEP + dep) * SEQ + kpos) = u;
            }
        }
    }
}

// ---------------- fused attention v5: dbuf K, swapped QK^T; NT aw stores last ----------------
template <int CAUSAL>
__global__ __launch_bounds__(256, 2) void attn_kernel(const unsigned short* __restrict__ Q, int ldq,
                                                      const unsigned short* __restrict__ Kp, int ldk,
                                                      const unsigned short* __restrict__ Vt,
                                                      const float* __restrict__ pad,
                                                      float* __restrict__ aw,
                                                      unsigned short* __restrict__ ctx) {
    __shared__ unsigned short Ks[2][128 * 64];
    __shared__ unsigned short Pch[32 * 128];
    __shared__ float redm[4][32];
    __shared__ float reds[4][32];
    const int t = threadIdx.x, lane = t & 63, w = t >> 6;
    const int lr = lane & 15, g = lane >> 4;
    const int id = blockIdx.x;
    const int bh = (id & 7) + ((id >> 8) << 3);
    const int qt = (id >> 3) & 31;
    const int q0 = qt * 32;
    const int b = bh >> 4, h = bh & 15;
    const size_t qbase = (size_t)b * SEQ * ldq + (size_t)h * DEP;
    const size_t kbase = (size_t)b * SEQ * ldk + (size_t)h * DEP;
    const int cmax = CAUSAL ? (q0 >> 7) + 1 : 8;

    const int srow = lane >> 3;
    const int sslot = (lane & 7) ^ srow;

    short8 aq[2][2];
#pragma unroll
    for (int p = 0; p < 2; ++p)
#pragma unroll
        for (int ks = 0; ks < 2; ++ks)
            aq[p][ks] = *(const short8*)(Q + qbase + (size_t)(q0 + p * 16 + lr) * ldq + ks * 32 + g * 8);

    f32x4 acc[2][8][2];
#pragma unroll
    for (int p = 0; p < 2; ++p)
#pragma unroll
        for (int c = 0; c < 8; ++c)
#pragma unroll
            for (int bn = 0; bn < 2; ++bn)
#pragma unroll
                for (int j = 0; j < 4; ++j) acc[p][c][bn][j] = 0.f;

    // ---- QK^T with prefetch ----
    {
#pragma unroll
        for (int i = 0; i < 4; ++i) {
            int rb = w * 32 + i * 8;
            gload16(Kp + kbase + (size_t)(rb + srow) * ldk + sslot * 8, &Ks[0][rb * 64]);
        }
    }
#pragma unroll
    for (int c = 0; c < 8; ++c) {
        if (c < cmax) {
            __syncthreads();
            if (c + 1 < cmax) {
#pragma unroll
                for (int i = 0; i < 4; ++i) {
                    int rb = w * 32 + i * 8;
                    gload16(Kp + kbase + (size_t)((c + 1) * 128 + rb + srow) * ldk + sslot * 8,
                            &Ks[(c + 1) & 1][rb * 64]);
                }
            }
#pragma unroll
            for (int ks = 0; ks < 2; ++ks)
#pragma unroll
                for (int bn = 0; bn < 2; ++bn) {
                    int row = w * 32 + bn * 16 + lr;
                    short8 bk = *(const short8*)((const char*)&Ks[c & 1][0] + row * 128 +
                                                 ((ks * 64 + g * 16) ^ ((lr & 7) << 4)));
                    acc[0][c][bn] = __builtin_amdgcn_mfma_f32_16x16x32_bf16(bk, aq[0][ks], acc[0][c][bn], 0, 0, 0);
                    acc[1][c][bn] = __builtin_amdgcn_mfma_f32_16x16x32_bf16(bk, aq[1][ks], acc[1][c][bn], 0, 0, 0);
                }
        }
    }

    // ---- scale + masks + row max ----
    float mrow[2] = {-1e30f, -1e30f};
#pragma unroll
    for (int c = 0; c < 8; ++c) {
        if (c < cmax) {
#pragma unroll
            for (int bn = 0; bn < 2; ++bn) {
                int k4 = c * 128 + w * 32 + bn * 16 + g * 4;
                f32x4 pv = {0.f, 0.f, 0.f, 0.f};
                if (pad) pv = *(const f32x4*)(pad + (size_t)b * SEQ + k4);
#pragma unroll
                for (int p = 0; p < 2; ++p) {
                    int q = q0 + p * 16 + lr;
#pragma unroll
                    for (int i = 0; i < 4; ++i) {
                        float v = acc[p][c][bn][i] * 0.125f + pv[i] * -1e9f;
                        if (CAUSAL && (k4 + i) > q) v = -1e30f;
                        acc[p][c][bn][i] = v;
                        mrow[p] = fmaxf(mrow[p], v);
                    }
                }
            }
        }
    }
#pragma unroll
    for (int p = 0; p < 2; ++p) {
        mrow[p] = fmaxf(mrow[p], __shfl_xor(mrow[p], 16));
        mrow[p] = fmaxf(mrow[p], __shfl_xor(mrow[p], 32));
    }
    if (lane < 16) { redm[w][lr] = mrow[0]; redm[w][16 + lr] = mrow[1]; }
    __syncthreads();
    float Mv[2];
#pragma unroll
    for (int p = 0; p < 2; ++p)
        Mv[p] = fmaxf(fmaxf(redm[0][p * 16 + lr], redm[1][p * 16 + lr]),
                      fmaxf(redm[2][p * 16 + lr], redm[3][p * 16 + lr]));

    // ---- exp + row sum ----
    float srw[2] = {0.f, 0.f};
#pragma unroll
    for (int c = 0; c < 8; ++c) {
        if (c < cmax) {
#pragma unroll
            for (int p = 0; p < 2; ++p)
#pragma unroll
                for (int bn = 0; bn < 2; ++bn)
#pragma unroll
                    for (int i = 0; i < 4; ++i) {
                        float e = __expf(acc[p][c][bn][i] - Mv[p]);
                        acc[p][c][bn][i] = e;
                        srw[p] += e;
                    }
        }
    }
#pragma unroll
    for (int p = 0; p < 2; ++p) {
        srw[p] += __shfl_xor(srw[p], 16);
        srw[p] += __shfl_xor(srw[p], 32);
    }
    if (lane < 16) { reds[w][lr] = srw[0]; reds[w][16 + lr] = srw[1]; }
    __syncthreads();
    float inv[2];
#pragma unroll
    for (int p = 0; p < 2; ++p)
        inv[p] = 1.0f / (reds[0][p * 16 + lr] + reds[1][p * 16 + lr] +
                         reds[2][p * 16 + lr] + reds[3][p * 16 + lr]);

    // ---- PV FIRST ----
    f32x4 acc2[2];
#pragma unroll
    for (int p = 0; p < 2; ++p)
#pragma unroll
        for (int j = 0; j < 4; ++j) acc2[p][j] = 0.f;
    char* pch = (char*)Pch;
    const int sw = (lr & 7) << 4;
#pragma unroll
    for (int c = 0; c < 8; ++c) {
        if (c < cmax) {
            __syncthreads();
#pragma unroll
            for (int p = 0; p < 2; ++p)
#pragma unroll
                for (int bn = 0; bn < 2; ++bn) {
                    us4 u;
#pragma unroll
                    for (int i = 0; i < 4; ++i) u[i] = f2bf(acc[p][c][bn][i] * inv[p]);
                    *(us4*)(pch + (p * 16 + lr) * 256 + ((w * 64 + bn * 32 + g * 8) ^ sw)) = u;
                }
            __syncthreads();
#pragma unroll
            for (int ks = 0; ks < 4; ++ks) {
                short8 bf = *(const short8*)(Vt + ((size_t)bh * DEP + w * 16 + lr) * SEQ + c * 128 + ks * 32 + g * 8);
#pragma unroll
                for (int p = 0; p < 2; ++p) {
                    short8 af = *(const short8*)(pch + (p * 16 + lr) * 256 + ((ks * 64 + g * 16) ^ sw));
                    acc2[p] = __builtin_amdgcn_mfma_f32_16x16x32_bf16(af, bf, acc2[p], 0, 0, 0);
                }
            }
        }
    }
#pragma unroll
    for (int p = 0; p < 2; ++p)
#pragma unroll
        for (int i = 0; i < 4; ++i)
            ctx[((size_t)b * SEQ + q0 + p * 16 + g * 4 + i) * DM + h * DEP + w * 16 + lr] = f2bf(acc2[p][i]);

    // ---- aw writes LAST, non-temporal (never re-read; don't pollute L2/L3) ----
#pragma unroll
    for (int p = 0; p < 2; ++p) {
        float* awrow = aw + ((size_t)bh * SEQ + q0 + p * 16 + lr) * SEQ;
#pragma unroll
        for (int c = 0; c < 8; ++c)
#pragma unroll
            for (int bn = 0; bn < 2; ++bn) {
                f32x4 o = {0.f, 0.f, 0.f, 0.f};
                if (c < cmax) {
#pragma unroll
                    for (int i = 0; i < 4; ++i) o[i] = acc[p][c][bn][i] * inv[p];
                }
                __builtin_nontemporal_store(o, (f32x4*)(awrow + c * 128 + w * 32 + bn * 16 + g * 4));
            }
    }
}

// ---------------- residual + layernorm: out = LN(X [+ X2] + R) ----------------
template <int WB, int X2EN, int NTF>
__global__ __launch_bounds__(256) void ln_kernel(const float* __restrict__ X,
                                                 const float* __restrict__ X2,
                                                 const float* __restrict__ R,
                                                 const float* __restrict__ gamma,
                                                 const float* __restrict__ beta,
                                                 float* __restrict__ outF,
                                                 unsigned short* __restrict__ outB) {
    size_t row = blockIdx.x;
    const int t = threadIdx.x;
    float4 a = ((const float4*)(X + (row << 10)))[t];
    float4 r = ((const float4*)(R + (row << 10)))[t];
    float v0 = a.x + r.x, v1 = a.y + r.y, v2 = a.z + r.z, v3 = a.w + r.w;
    if (X2EN) {
        float4 a2 = ((const float4*)(X2 + (row << 10)))[t];
        v0 += a2.x; v1 += a2.y; v2 += a2.z; v3 += a2.w;
    }
    float s = v0 + v1 + v2 + v3;
    float q = v0 * v0 + v1 * v1 + v2 * v2 + v3 * v3;
#pragma unroll
    for (int off = 32; off; off >>= 1) {
        s += __shfl_down(s, off);
        q += __shfl_down(q, off);
    }
    __shared__ float rs[4], rq[4];
    if ((t & 63) == 0) { rs[t >> 6] = s; rq[t >> 6] = q; }
    __syncthreads();
    s = rs[0] + rs[1] + rs[2] + rs[3];
    q = rq[0] + rq[1] + rq[2] + rq[3];
    float mean = s * (1.0f / 1024.0f);
    float var = q * (1.0f / 1024.0f) - mean * mean;
    float inv = rsqrtf(var + 1e-6f);
    float g0 = gamma[t * 4], g1 = gamma[t * 4 + 1], g2 = gamma[t * 4 + 2], g3 = gamma[t * 4 + 3];
    float b0 = beta[t * 4], b1 = beta[t * 4 + 1], b2 = beta[t * 4 + 2], b3 = beta[t * 4 + 3];
    f32x4 o;
    o[0] = (v0 - mean) * inv * g0 + b0;
    o[1] = (v1 - mean) * inv * g1 + b1;
    o[2] = (v2 - mean) * inv * g2 + b2;
    o[3] = (v3 - mean) * inv * g3 + b3;
    if (NTF) __builtin_nontemporal_store(o, (f32x4*)(outF + (row << 10)) + t);
    else ((f32x4*)(outF + (row << 10)))[t] = o;
    if (WB) {
        us4 u;
        u[0] = f2bf(o[0]); u[1] = f2bf(o[1]); u[2] = f2bf(o[2]); u[3] = f2bf(o[3]);
        ((us4*)(outB + (row << 10)))[t] = u;
    }
}

extern "C" void kernel_launch(void* const* d_in, const int* in_sizes, int n_in,
                              void* d_out, int out_size, void* d_ws, size_t ws_size,
                              hipStream_t stream) {
    const float* x = (const float*)d_in[0];
    const float* enc = (const float*)d_in[1];
    const float* pad = (const float*)d_in[3];
    const float* wq1 = (const float*)d_in[4];  const float* bq1 = (const float*)d_in[5];
    const float* wk1 = (const float*)d_in[6];  const float* bk1 = (const float*)d_in[7];
    const float* wv1 = (const float*)d_in[8];  const float* bv1 = (const float*)d_in[9];
    const float* wo1 = (const float*)d_in[10]; const float* bo1 = (const float*)d_in[11];
    const float* wq2 = (const float*)d_in[12]; const float* bq2 = (const float*)d_in[13];
    const float* wk2 = (const float*)d_in[14]; const float* bk2 = (const float*)d_in[15];
    const float* wv2 = (const float*)d_in[16]; const float* bv2 = (const float*)d_in[17];
    const float* wo2 = (const float*)d_in[18]; const float* bo2 = (const float*)d_in[19];
    const float* wf1 = (const float*)d_in[20]; const float* bf1 = (const float*)d_in[21];
    const float* wf2 = (const float*)d_in[22]; const float* bf2 = (const float*)d_in[23];
    const float* g1 = (const float*)d_in[24]; const float* be1 = (const float*)d_in[25];
    const float* g2 = (const float*)d_in[26]; const float* be2 = (const float*)d_in[27];
    const float* g3 = (const float*)d_in[28]; const float* be3 = (const float*)d_in[29];

    float* out3 = (float*)d_out;
    float* aw1 = out3 + (size_t)NB * SEQ * DM;
    float* aw2 = aw1 + (size_t)NB * NH * SEQ * SEQ;

    char* ws = (char*)d_ws;
    size_t off = 0;
    auto take = [&](size_t n) { char* p = ws + off; off += (n + 255) & ~(size_t)255; return p; };
    const size_t SZ_SD_BF = (size_t)NB * SEQ * DM * 2;
    const size_t SZ_SD_F  = (size_t)NB * SEQ * DM * 4;
    const size_t SZ_DD_BF = (size_t)DM * DM * 2;

    unsigned short* wqkv1t = (unsigned short*)take(3 * SZ_DD_BF);
    unsigned short* wq2t   = (unsigned short*)take(SZ_DD_BF);
    unsigned short* wkv2t  = (unsigned short*)take(2 * SZ_DD_BF);
    unsigned short* wo1t   = (unsigned short*)take(SZ_DD_BF);
    unsigned short* wo2t   = (unsigned short*)take(SZ_DD_BF);
    unsigned short* wf1t   = (unsigned short*)take((size_t)DM * DFFN * 2);
    unsigned short* wf2t   = (unsigned short*)take((size_t)DFFN * DM * 2);
    float* bqkv1 = (float*)take(3 * DM * 4);
    float* bkv2  = (float*)take(2 * DM * 4);
    unsigned short* xb    = (unsigned short*)take(SZ_SD_BF);
    unsigned short* encb  = (unsigned short*)take(SZ_SD_BF);
    unsigned short* qkv1b = (unsigned short*)take(3 * SZ_SD_BF);
    unsigned short* v1t   = (unsigned short*)take(SZ_SD_BF);
    unsigned short* qb    = (unsigned short*)take(SZ_SD_BF);
    unsigned short* kv2b  = (unsigned short*)take(2 * SZ_SD_BF);
    unsigned short* v2t   = (unsigned short*)take(SZ_SD_BF);
    unsigned short* ctx   = (unsigned short*)take(SZ_SD_BF);
    float* goutf  = (float*)take(SZ_SD_F);
    float* gout2f = (float*)take(SZ_SD_F);
    float* out1f  = (float*)take(SZ_SD_F);
    unsigned short* out1b = (unsigned short*)take(SZ_SD_BF);
    float* out2f  = (float*)take(SZ_SD_F);
    unsigned short* out2b = (unsigned short*)take(SZ_SD_BF);
    unsigned short* ffn1b = (unsigned short*)take((size_t)NB * SEQ * DFFN * 2);

    // ----- prep: 3 launches -----
    {
        int n4 = NB * SEQ * DM / 4;
        dim3 gc((n4 + 255) / 256, 2);
        cast2_kernel<<<gc, 256, 0, stream>>>(x, enc, xb, encb, n4);
    }
    {
        P10 s;
        s.p[0] = wq1; s.p[1] = wk1; s.p[2] = wv1; s.p[3] = wq2;
        s.p[4] = wk2; s.p[5] = wv2; s.p[6] = wo1; s.p[7] = wo2;
        s.p[8] = wf1; s.p[9] = wf2;
        castTall_kernel<<<4096, 256, 0, stream>>>(s, wqkv1t, wf1t, wf2t);
    }
    biaspack_kernel<<<20, 256, 0, stream>>>(bq1, bk1, bv1, bk2, bv2, bqkv1, bkv2);

    const int M = NB * SEQ;
    dim3 gQKV(3 * DM / 128, M / 128);
    dim3 gKV(2 * DM / 128, M / 128);
    dim3 gDD64(DM / 128, M / 64);
    dim3 gDF(DFFN / 128, M / 128);
    dim3 gF2(DM / 128, M / 128, 2);

    // ---- MHA1 (self, causal) ----
    gemm_kernel<128, 128, 32, 1, 0, 1, 0, 1><<<gQKV, 256, 0, stream>>>(xb, wqkv1t, bqkv1, qkv1b, nullptr, nullptr, v1t, 2048, M, 3 * DM, DM);
    attn_kernel<1><<<2048, 256, 0, stream>>>(qkv1b, 3 * DM, qkv1b + DM, 3 * DM, v1t, nullptr, aw1, ctx);
    gemm_kernel<64, 128, 64, 1, 0, 0, 1, 0><<<gDD64, 256, 0, stream>>>(ctx, wo1t, bo1, nullptr, goutf, nullptr, nullptr, 0, M, DM, DM);
    ln_kernel<1, 0, 0><<<M, 256, 0, stream>>>(goutf, nullptr, x, g1, be1, out1f, out1b);

    // ---- MHA2 (cross, padding mask) ----
    gemm_kernel<64, 128, 64, 1, 0, 1, 0, 0><<<gDD64, 256, 0, stream>>>(out1b, wq2t, bq2, qb, nullptr, nullptr, nullptr, 0, M, DM, DM);
    gemm_kernel<128, 128, 32, 1, 0, 1, 0, 1><<<gKV, 256, 0, stream>>>(encb, wkv2t, bkv2, kv2b, nullptr, nullptr, v2t, 1024, M, 2 * DM, DM);
    attn_kernel<0><<<2048, 256, 0, stream>>>(qb, DM, kv2b, 2 * DM, v2t, pad, aw2, ctx);
    gemm_kernel<64, 128, 64, 1, 0, 0, 1, 0><<<gDD64, 256, 0, stream>>>(ctx, wo2t, bo2, nullptr, goutf, nullptr, nullptr, 0, M, DM, DM);
    ln_kernel<1, 0, 0><<<M, 256, 0, stream>>>(goutf, nullptr, out1f, g2, be2, out2f, out2b);

    // ---- FFN ----
    gemm_kernel<128, 128, 32, 1, 1, 1, 0, 0><<<gDF, 256, 0, stream>>>(out2b, wf1t, bf1, ffn1b, nullptr, nullptr, nullptr, 0, M, DFFN, DM);
    gemm_kernel<128, 128, 32, 2, 0, 0, 1, 0><<<gF2, 256, 0, stream>>>(ffn1b, wf2t, bf2, nullptr, goutf, gout2f, nullptr, 0, M, DM, DFFN);
    ln_kernel<0, 1, 1><<<M, 256, 0, stream>>>(goutf, gout2f, out2f, g3, be3, out3, nullptr);
}

// Round 10
// 495.193 us; speedup vs baseline: 1.1924x; 1.0202x over previous
//
#include <hip/hip_runtime.h>

#define NB 4
#define SEQ 1024
#define DM 1024
#define NH 16
#define DEP 64
#define DFFN 4096

typedef __attribute__((ext_vector_type(8))) short short8;
typedef __attribute__((ext_vector_type(4))) float f32x4;
typedef __attribute__((ext_vector_type(4))) unsigned short us4;

__device__ __forceinline__ unsigned short f2bf(float f) {
    union { float f; unsigned int u; } v; v.f = f;
    unsigned int u = v.u;
    return (unsigned short)((u + 0x7FFFu + ((u >> 16) & 1u)) >> 16);
}

__device__ __forceinline__ void gload16(const void* g, void* l) {
    __builtin_amdgcn_global_load_lds((const __attribute__((address_space(1))) unsigned int*)g,
                                     (__attribute__((address_space(3))) unsigned int*)l, 16, 0, 0);
}

// ---------------- dual cast f32 -> bf16 (NT loads) ----------------
__global__ __launch_bounds__(256) void cast2_kernel(const float* __restrict__ a,
                                                    const float* __restrict__ b,
                                                    unsigned short* __restrict__ oa,
                                                    unsigned short* __restrict__ ob, int n4) {
    int i = blockIdx.x * 256 + threadIdx.x;
    const float* in = blockIdx.y ? b : a;
    unsigned short* out = blockIdx.y ? ob : oa;
    if (i < n4) {
        f32x4 f = __builtin_nontemporal_load((const f32x4*)in + i);
        us4 u;
        u[0] = f2bf(f[0]); u[1] = f2bf(f[1]); u[2] = f2bf(f[2]); u[3] = f2bf(f[3]);
        ((us4*)out)[i] = u;
    }
}

// ---------------- batched transpose-cast: 8 squares + wf1 + wf2 ----------------
struct P10 { const float* p[10]; };
__global__ __launch_bounds__(256) void castTall_kernel(P10 s,
                                                       unsigned short* __restrict__ wsq,
                                                       unsigned short* __restrict__ wf1t,
                                                       unsigned short* __restrict__ wf2t) {
    __shared__ float tile[64][65];
    const int tid = blockIdx.x, t = threadIdx.x;
    const float* in; unsigned short* out; int R, C, r0, c0;
    if (tid < 2048) {
        int wi = tid >> 8, t2 = tid & 255;
        in = s.p[wi]; out = wsq + (size_t)wi * DM * DM; R = DM; C = DM;
        r0 = (t2 >> 4) * 64; c0 = (t2 & 15) * 64;
    } else if (tid < 3072) {
        int t2 = tid - 2048;
        in = s.p[8]; out = wf1t; R = DM; C = DFFN;
        r0 = (t2 >> 6) * 64; c0 = (t2 & 63) * 64;
    } else {
        int t2 = tid - 3072;
        in = s.p[9]; out = wf2t; R = DFFN; C = DM;
        r0 = (t2 >> 4) * 64; c0 = (t2 & 15) * 64;
    }
#pragma unroll
    for (int p = 0; p < 4; ++p) {
        int r = p * 16 + (t >> 4), c = (t & 15) * 4;
        f32x4 f = __builtin_nontemporal_load((const f32x4*)(in + (size_t)(r0 + r) * C + c0 + c));
        tile[r][c] = f[0]; tile[r][c + 1] = f[1]; tile[r][c + 2] = f[2]; tile[r][c + 3] = f[3];
    }
    __syncthreads();
#pragma unroll
    for (int p = 0; p < 4; ++p) {
        int n = p * 16 + (t >> 4), k = (t & 15) * 4;
        us4 u;
#pragma unroll
        for (int j = 0; j < 4; ++j) u[j] = f2bf(tile[k + j][n]);
        *(us4*)(out + (size_t)(c0 + n) * R + r0 + k) = u;
    }
}

// ---------------- bias concat pack ----------------
__global__ __launch_bounds__(256) void biaspack_kernel(const float* __restrict__ bq1,
                                                       const float* __restrict__ bk1,
                                                       const float* __restrict__ bv1,
                                                       const float* __restrict__ bk2,
                                                       const float* __restrict__ bv2,
                                                       float* __restrict__ bqkv1,
                                                       float* __restrict__ bkv2) {
    int i = blockIdx.x * 256 + threadIdx.x;
    if (i < 1024) bqkv1[i] = bq1[i];
    else if (i < 2048) bqkv1[i] = bk1[i - 1024];
    else if (i < 3072) bqkv1[i] = bv1[i - 2048];
    else if (i < 4096) bkv2[i - 3072] = bk2[i - 3072];
    else if (i < 5120) bkv2[i - 3072] = bv2[i - 4096];
}

// ---------------- bf16 GEMM: 3-buffer ring, 2-deep prefetch, counted vmcnt (T3/T4) ----------------
template <int BM, int BN, int BK, int KSPLIT, int RELU, int WB, int WF, int WVT>
__global__ __launch_bounds__(256) void gemm_kernel(const unsigned short* __restrict__ A,
                                                   const unsigned short* __restrict__ Wt,
                                                   const float* __restrict__ bias,
                                                   unsigned short* __restrict__ Cb,
                                                   float* __restrict__ Cf,
                                                   float* __restrict__ Cf2,
                                                   unsigned short* __restrict__ Vt,
                                                   int vstart,
                                                   int M, int N, int K) {
    constexpr int AM = BM / 32;
    constexpr int KS = BK / 32;
    constexpr int LPR = BK / 8;
    constexpr int RPI = 64 / LPR;
    constexpr int AR = (BM / 4) / RPI;
    constexpr int BR = (BN / 4) / RPI;
    constexpr int NLD = AR + BR;         // per-thread loads per staged tile
    __shared__ unsigned short As[3][BM * BK];
    __shared__ unsigned short Bs[3][BN * BK];
    const int t = threadIdx.x;
    const int lane = t & 63, w = t >> 6;
    const int nwg = gridDim.x * gridDim.y;
    const int rawid = blockIdx.y * gridDim.x + blockIdx.x;
    const int swz = (rawid & 7) * (nwg >> 3) + (rawid >> 3);
    const int m0 = (swz / gridDim.x) * BM, n0 = (swz % gridDim.x) * BN;
    const int wm = (w >> 1) * (BM / 2), wn = (w & 1) * (BN / 2);
    const int lr = lane & 15, g = lane >> 4, kb = g * 8;
    const int srow = lane / LPR, scol = (lane % LPR) * 8;
    const int kofs = (KSPLIT == 2 && blockIdx.z) ? K / 2 : 0;
    const int Keff = (KSPLIT == 2) ? K / 2 : K;
    const int nk = Keff / BK;

    f32x4 acc[AM][4];
#pragma unroll
    for (int a = 0; a < AM; ++a)
#pragma unroll
        for (int b = 0; b < 4; ++b)
#pragma unroll
            for (int j = 0; j < 4; ++j) acc[a][b][j] = 0.f;

    auto STAGE = [&](int buf, int kt) {
#pragma unroll
        for (int ia = 0; ia < AR; ++ia) {
            int rb = w * (BM / 4) + ia * RPI;
            gload16(A + (size_t)(m0 + rb + srow) * K + kt + scol, &As[buf][rb * BK]);
        }
#pragma unroll
        for (int ib = 0; ib < BR; ++ib) {
            int rb = w * (BN / 4) + ib * RPI;
            gload16(Wt + (size_t)(n0 + rb + srow) * K + kt + scol, &Bs[buf][rb * BK]);
        }
    };

    STAGE(0, kofs);
    if (nk > 1) STAGE(1, kofs + BK);
    int sb = 2, cb = 0;
    for (int i = 0; i < nk; ++i) {
        if (i + 2 < nk) {
            STAGE(sb, kofs + (i + 2) * BK);
            if (++sb == 3) sb = 0;
            asm volatile("s_waitcnt vmcnt(%0)" :: "n"(2 * NLD) : "memory");
        } else if (i + 1 < nk) {
            asm volatile("s_waitcnt vmcnt(%0)" :: "n"(NLD) : "memory");
        } else {
            asm volatile("s_waitcnt vmcnt(0)" ::: "memory");
        }
        __builtin_amdgcn_s_barrier();   // all waves' tile-i loads retired

        short8 af[AM][KS], bfr[4][KS];
#pragma unroll
        for (int ii = 0; ii < AM; ++ii)
#pragma unroll
            for (int ks = 0; ks < KS; ++ks)
                af[ii][ks] = *(const short8*)&As[cb][(wm + ii * 16 + lr) * BK + ks * 32 + kb];
#pragma unroll
        for (int ii = 0; ii < 4; ++ii)
#pragma unroll
            for (int ks = 0; ks < KS; ++ks)
                bfr[ii][ks] = *(const short8*)&Bs[cb][(wn + ii * 16 + lr) * BK + ks * 32 + kb];
#pragma unroll
        for (int ks = 0; ks < KS; ++ks)
#pragma unroll
            for (int am = 0; am < AM; ++am)
#pragma unroll
                for (int bn = 0; bn < 4; ++bn)
                    acc[am][bn] = __builtin_amdgcn_mfma_f32_16x16x32_bf16(af[am][ks], bfr[bn][ks], acc[am][bn], 0, 0, 0);
        if (++cb == 3) cb = 0;
        __builtin_amdgcn_s_barrier();   // reads done before this buf is re-staged
    }

    float* cfo = (KSPLIT == 2 && blockIdx.z) ? Cf2 : Cf;
    const bool addb = bias && (KSPLIT == 1 || blockIdx.z == 0);
#pragma unroll
    for (int am = 0; am < AM; ++am) {
#pragma unroll
        for (int bn = 0; bn < 4; ++bn) {
            int col = n0 + wn + bn * 16 + lr;
            float bv = addb ? bias[col] : 0.f;
            int rowb = m0 + wm + am * 16 + g * 4;
            float vv[4];
#pragma unroll
            for (int i = 0; i < 4; ++i) {
                float v = acc[am][bn][i] + bv;
                if (RELU) v = v > 0.f ? v : 0.f;
                vv[i] = v;
                if (WF) cfo[(size_t)(rowb + i) * N + col] = v;
                if (WB) Cb[(size_t)(rowb + i) * N + col] = f2bf(v);
            }
            if (WVT && col >= vstart) {
                int h = (col - vstart) >> 6, dep = (col - vstart) & 63;
                int b = rowb >> 10, kpos = rowb & 1023;
                us4 u;
#pragma unroll
                for (int i = 0; i < 4; ++i) u[i] = f2bf(vv[i]);
                *(us4*)(Vt + ((size_t)(b * NH + h) * DEP + dep) * SEQ + kpos) = u;
            }
        }
    }
}

// ---------------- fused attention v6: barrier-free ring-3 QK pipeline; NT aw last ----------------
// Each wave stages exactly the K-rows it reads -> no cross-wave hazard in QK; per-wave vmcnt only.
template <int CAUSAL>
__global__ __launch_bounds__(256, 2) void attn_kernel(const unsigned short* __restrict__ Q, int ldq,
                                                      const unsigned short* __restrict__ Kp, int ldk,
                                                      const unsigned short* __restrict__ Vt,
                                                      const float* __restrict__ pad,
                                                      float* __restrict__ aw,
                                                      unsigned short* __restrict__ ctx) {
    __shared__ unsigned short Ks[3][128 * 64];  // 48 KB ring, source-swizzled
    __shared__ unsigned short Pch[32 * 128];    // 8 KB, 16B-XOR swizzled
    __shared__ float redm[4][32];
    __shared__ float reds[4][32];
    const int t = threadIdx.x, lane = t & 63, w = t >> 6;
    const int lr = lane & 15, g = lane >> 4;
    const int id = blockIdx.x;
    const int bh = (id & 7) + ((id >> 8) << 3);
    const int qt = (id >> 3) & 31;
    const int q0 = qt * 32;
    const int b = bh >> 4, h = bh & 15;
    const size_t qbase = (size_t)b * SEQ * ldq + (size_t)h * DEP;
    const size_t kbase = (size_t)b * SEQ * ldk + (size_t)h * DEP;
    const int cmax = CAUSAL ? (q0 >> 7) + 1 : 8;

    const int srow = lane >> 3;
    const int sslot = (lane & 7) ^ srow;

    short8 aq[2][2];
#pragma unroll
    for (int p = 0; p < 2; ++p)
#pragma unroll
        for (int ks = 0; ks < 2; ++ks)
            aq[p][ks] = *(const short8*)(Q + qbase + (size_t)(q0 + p * 16 + lr) * ldq + ks * 32 + g * 8);

    f32x4 acc[2][8][2];
#pragma unroll
    for (int p = 0; p < 2; ++p)
#pragma unroll
        for (int c = 0; c < 8; ++c)
#pragma unroll
            for (int bn = 0; bn < 2; ++bn)
#pragma unroll
                for (int j = 0; j < 4; ++j) acc[p][c][bn][j] = 0.f;

#define STAGE_K(BUF, CH)                                                                   \
    {                                                                                      \
        _Pragma("unroll") for (int i_ = 0; i_ < 4; ++i_) {                                 \
            int rb_ = w * 32 + i_ * 8;                                                     \
            gload16(Kp + kbase + (size_t)((CH) * 128 + rb_ + srow) * ldk + sslot * 8,      \
                    &Ks[BUF][rb_ * 64]);                                                   \
        }                                                                                  \
    }

    // ---- QK^T: barrier-free per-wave pipeline (2-deep prefetch) ----
    STAGE_K(0, 0);
    if (1 < cmax) STAGE_K(1, 1);
#pragma unroll
    for (int c = 0; c < 8; ++c) {
        if (c < cmax) {
            if (c + 2 < cmax) {
                STAGE_K((c + 2) % 3, c + 2);
                asm volatile("s_waitcnt vmcnt(8)" ::: "memory");
            } else if (c + 1 < cmax) {
                asm volatile("s_waitcnt vmcnt(4)" ::: "memory");
            } else {
                asm volatile("s_waitcnt vmcnt(0)" ::: "memory");
            }
#pragma unroll
            for (int ks = 0; ks < 2; ++ks)
#pragma unroll
                for (int bn = 0; bn < 2; ++bn) {
                    int row = w * 32 + bn * 16 + lr;
                    short8 bk = *(const short8*)((const char*)&Ks[c % 3][0] + row * 128 +
                                                 ((ks * 64 + g * 16) ^ ((lr & 7) << 4)));
                    acc[0][c][bn] = __builtin_amdgcn_mfma_f32_16x16x32_bf16(bk, aq[0][ks], acc[0][c][bn], 0, 0, 0);
                    acc[1][c][bn] = __builtin_amdgcn_mfma_f32_16x16x32_bf16(bk, aq[1][ks], acc[1][c][bn], 0, 0, 0);
                }
        }
    }
#undef STAGE_K

    // ---- scale + masks + row max ----
    float mrow[2] = {-1e30f, -1e30f};
#pragma unroll
    for (int c = 0; c < 8; ++c) {
        if (c < cmax) {
#pragma unroll
            for (int bn = 0; bn < 2; ++bn) {
                int k4 = c * 128 + w * 32 + bn * 16 + g * 4;
                f32x4 pv = {0.f, 0.f, 0.f, 0.f};
                if (pad) pv = *(const f32x4*)(pad + (size_t)b * SEQ + k4);
#pragma unroll
                for (int p = 0; p < 2; ++p) {
                    int q = q0 + p * 16 + lr;
#pragma unroll
                    for (int i = 0; i < 4; ++i) {
                        float v = acc[p][c][bn][i] * 0.125f + pv[i] * -1e9f;
                        if (CAUSAL && (k4 + i) > q) v = -1e30f;
                        acc[p][c][bn][i] = v;
                        mrow[p] = fmaxf(mrow[p], v);
                    }
                }
            }
        }
    }
#pragma unroll
    for (int p = 0; p < 2; ++p) {
        mrow[p] = fmaxf(mrow[p], __shfl_xor(mrow[p], 16));
        mrow[p] = fmaxf(mrow[p], __shfl_xor(mrow[p], 32));
    }
    if (lane < 16) { redm[w][lr] = mrow[0]; redm[w][16 + lr] = mrow[1]; }
    __syncthreads();
    float Mv[2];
#pragma unroll
    for (int p = 0; p < 2; ++p)
        Mv[p] = fmaxf(fmaxf(redm[0][p * 16 + lr], redm[1][p * 16 + lr]),
                      fmaxf(redm[2][p * 16 + lr], redm[3][p * 16 + lr]));

    // ---- exp + row sum ----
    float srw[2] = {0.f, 0.f};
#pragma unroll
    for (int c = 0; c < 8; ++c) {
        if (c < cmax) {
#pragma unroll
            for (int p = 0; p < 2; ++p)
#pragma unroll
                for (int bn = 0; bn < 2; ++bn)
#pragma unroll
                    for (int i = 0; i < 4; ++i) {
                        float e = __expf(acc[p][c][bn][i] - Mv[p]);
                        acc[p][c][bn][i] = e;
                        srw[p] += e;
                    }
        }
    }
#pragma unroll
    for (int p = 0; p < 2; ++p) {
        srw[p] += __shfl_xor(srw[p], 16);
        srw[p] += __shfl_xor(srw[p], 32);
    }
    if (lane < 16) { reds[w][lr] = srw[0]; reds[w][16 + lr] = srw[1]; }
    __syncthreads();
    float inv[2];
#pragma unroll
    for (int p = 0; p < 2; ++p)
        inv[p] = 1.0f / (reds[0][p * 16 + lr] + reds[1][p * 16 + lr] +
                         reds[2][p * 16 + lr] + reds[3][p * 16 + lr]);

    // ---- PV (cross-wave Pch -> barriers stay) ----
    f32x4 acc2[2];
#pragma unroll
    for (int p = 0; p < 2; ++p)
#pragma unroll
        for (int j = 0; j < 4; ++j) acc2[p][j] = 0.f;
    char* pch = (char*)Pch;
    const int sw = (lr & 7) << 4;
#pragma unroll
    for (int c = 0; c < 8; ++c) {
        if (c < cmax) {
            __syncthreads();
#pragma unroll
            for (int p = 0; p < 2; ++p)
#pragma unroll
                for (int bn = 0; bn < 2; ++bn) {
                    us4 u;
#pragma unroll
                    for (int i = 0; i < 4; ++i) u[i] = f2bf(acc[p][c][bn][i] * inv[p]);
                    *(us4*)(pch + (p * 16 + lr) * 256 + ((w * 64 + bn * 32 + g * 8) ^ sw)) = u;
                }
            __syncthreads();
#pragma unroll
            for (int ks = 0; ks < 4; ++ks) {
                short8 bf = *(const short8*)(Vt + ((size_t)bh * DEP + w * 16 + lr) * SEQ + c * 128 + ks * 32 + g * 8);
#pragma unroll
                for (int p = 0; p < 2; ++p) {
                    short8 af = *(const short8*)(pch + (p * 16 + lr) * 256 + ((ks * 64 + g * 16) ^ sw));
                    acc2[p] = __builtin_amdgcn_mfma_f32_16x16x32_bf16(af, bf, acc2[p], 0, 0, 0);
                }
            }
        }
    }
#pragma unroll
    for (int p = 0; p < 2; ++p)
#pragma unroll
        for (int i = 0; i < 4; ++i)
            ctx[((size_t)b * SEQ + q0 + p * 16 + g * 4 + i) * DM + h * DEP + w * 16 + lr] = f2bf(acc2[p][i]);

    // ---- aw writes LAST, non-temporal ----
#pragma unroll
    for (int p = 0; p < 2; ++p) {
        float* awrow = aw + ((size_t)bh * SEQ + q0 + p * 16 + lr) * SEQ;
#pragma unroll
        for (int c = 0; c < 8; ++c)
#pragma unroll
            for (int bn = 0; bn < 2; ++bn) {
                f32x4 o = {0.f, 0.f, 0.f, 0.f};
                if (c < cmax) {
#pragma unroll
                    for (int i = 0; i < 4; ++i) o[i] = acc[p][c][bn][i] * inv[p];
                }
                __builtin_nontemporal_store(o, (f32x4*)(awrow + c * 128 + w * 32 + bn * 16 + g * 4));
            }
    }
}

// ---------------- residual + layernorm: out = LN(X [+ X2] + R) ----------------
template <int WB, int X2EN, int NTF>
__global__ __launch_bounds__(256) void ln_kernel(const float* __restrict__ X,
                                                 const float* __restrict__ X2,
                                                 const float* __restrict__ R,
                                                 const float* __restrict__ gamma,
                                                 const float* __restrict__ beta,
                                                 float* __restrict__ outF,
                                                 unsigned short* __restrict__ outB) {
    size_t row = blockIdx.x;
    const int t = threadIdx.x;
    float4 a = ((const float4*)(X + (row << 10)))[t];
    float4 r = ((const float4*)(R + (row << 10)))[t];
    float v0 = a.x + r.x, v1 = a.y + r.y, v2 = a.z + r.z, v3 = a.w + r.w;
    if (X2EN) {
        float4 a2 = ((const float4*)(X2 + (row << 10)))[t];
        v0 += a2.x; v1 += a2.y; v2 += a2.z; v3 += a2.w;
    }
    float s = v0 + v1 + v2 + v3;
    float q = v0 * v0 + v1 * v1 + v2 * v2 + v3 * v3;
#pragma unroll
    for (int off = 32; off; off >>= 1) {
        s += __shfl_down(s, off);
        q += __shfl_down(q, off);
    }
    __shared__ float rs[4], rq[4];
    if ((t & 63) == 0) { rs[t >> 6] = s; rq[t >> 6] = q; }
    __syncthreads();
    s = rs[0] + rs[1] + rs[2] + rs[3];
    q = rq[0] + rq[1] + rq[2] + rq[3];
    float mean = s * (1.0f / 1024.0f);
    float var = q * (1.0f / 1024.0f) - mean * mean;
    float inv = rsqrtf(var + 1e-6f);
    float g0 = gamma[t * 4], g1 = gamma[t * 4 + 1], g2 = gamma[t * 4 + 2], g3 = gamma[t * 4 + 3];
    float b0 = beta[t * 4], b1 = beta[t * 4 + 1], b2 = beta[t * 4 + 2], b3 = beta[t * 4 + 3];
    f32x4 o;
    o[0] = (v0 - mean) * inv * g0 + b0;
    o[1] = (v1 - mean) * inv * g1 + b1;
    o[2] = (v2 - mean) * inv * g2 + b2;
    o[3] = (v3 - mean) * inv * g3 + b3;
    if (NTF) __builtin_nontemporal_store(o, (f32x4*)(outF + (row << 10)) + t);
    else ((f32x4*)(outF + (row << 10)))[t] = o;
    if (WB) {
        us4 u;
        u[0] = f2bf(o[0]); u[1] = f2bf(o[1]); u[2] = f2bf(o[2]); u[3] = f2bf(o[3]);
        ((us4*)(outB + (row << 10)))[t] = u;
    }
}

extern "C" void kernel_launch(void* const* d_in, const int* in_sizes, int n_in,
                              void* d_out, int out_size, void* d_ws, size_t ws_size,
                              hipStream_t stream) {
    const float* x = (const float*)d_in[0];
    const float* enc = (const float*)d_in[1];
    const float* pad = (const float*)d_in[3];
    const float* wq1 = (const float*)d_in[4];  const float* bq1 = (const float*)d_in[5];
    const float* wk1 = (const float*)d_in[6];  const float* bk1 = (const float*)d_in[7];
    const float* wv1 = (const float*)d_in[8];  const float* bv1 = (const float*)d_in[9];
    const float* wo1 = (const float*)d_in[10]; const float* bo1 = (const float*)d_in[11];
    const float* wq2 = (const float*)d_in[12]; const float* bq2 = (const float*)d_in[13];
    const float* wk2 = (const float*)d_in[14]; const float* bk2 = (const float*)d_in[15];
    const float* wv2 = (const float*)d_in[16]; const float* bv2 = (const float*)d_in[17];
    const float* wo2 = (const float*)d_in[18]; const float* bo2 = (const float*)d_in[19];
    const float* wf1 = (const float*)d_in[20]; const float* bf1 = (const float*)d_in[21];
    const float* wf2 = (const float*)d_in[22]; const float* bf2 = (const float*)d_in[23];
    const float* g1 = (const float*)d_in[24]; const float* be1 = (const float*)d_in[25];
    const float* g2 = (const float*)d_in[26]; const float* be2 = (const float*)d_in[27];
    const float* g3 = (const float*)d_in[28]; const float* be3 = (const float*)d_in[29];

    float* out3 = (float*)d_out;
    float* aw1 = out3 + (size_t)NB * SEQ * DM;
    float* aw2 = aw1 + (size_t)NB * NH * SEQ * SEQ;

    char* ws = (char*)d_ws;
    size_t off = 0;
    auto take = [&](size_t n) { char* p = ws + off; off += (n + 255) & ~(size_t)255; return p; };
    const size_t SZ_SD_BF = (size_t)NB * SEQ * DM * 2;
    const size_t SZ_SD_F  = (size_t)NB * SEQ * DM * 4;
    const size_t SZ_DD_BF = (size_t)DM * DM * 2;

    unsigned short* wqkv1t = (unsigned short*)take(3 * SZ_DD_BF);
    unsigned short* wq2t   = (unsigned short*)take(SZ_DD_BF);
    unsigned short* wkv2t  = (unsigned short*)take(2 * SZ_DD_BF);
    unsigned short* wo1t   = (unsigned short*)take(SZ_DD_BF);
    unsigned short* wo2t   = (unsigned short*)take(SZ_DD_BF);
    unsigned short* wf1t   = (unsigned short*)take((size_t)DM * DFFN * 2);
    unsigned short* wf2t   = (unsigned short*)take((size_t)DFFN * DM * 2);
    float* bqkv1 = (float*)take(3 * DM * 4);
    float* bkv2  = (float*)take(2 * DM * 4);
    unsigned short* xb    = (unsigned short*)take(SZ_SD_BF);
    unsigned short* encb  = (unsigned short*)take(SZ_SD_BF);
    unsigned short* qkv1b = (unsigned short*)take(3 * SZ_SD_BF);
    unsigned short* v1t   = (unsigned short*)take(SZ_SD_BF);
    unsigned short* qb    = (unsigned short*)take(SZ_SD_BF);
    unsigned short* kv2b  = (unsigned short*)take(2 * SZ_SD_BF);
    unsigned short* v2t   = (unsigned short*)take(SZ_SD_BF);
    unsigned short* ctx   = (unsigned short*)take(SZ_SD_BF);
    float* goutf  = (float*)take(SZ_SD_F);
    float* gout2f = (float*)take(SZ_SD_F);
    float* out1f  = (float*)take(SZ_SD_F);
    unsigned short* out1b = (unsigned short*)take(SZ_SD_BF);
    float* out2f  = (float*)take(SZ_SD_F);
    unsigned short* out2b = (unsigned short*)take(SZ_SD_BF);
    unsigned short* ffn1b = (unsigned short*)take((size_t)NB * SEQ * DFFN * 2);

    // ----- prep: 3 launches -----
    {
        int n4 = NB * SEQ * DM / 4;
        dim3 gc((n4 + 255) / 256, 2);
        cast2_kernel<<<gc, 256, 0, stream>>>(x, enc, xb, encb, n4);
    }
    {
        P10 s;
        s.p[0] = wq1; s.p[1] = wk1; s.p[2] = wv1; s.p[3] = wq2;
        s.p[4] = wk2; s.p[5] = wv2; s.p[6] = wo1; s.p[7] = wo2;
        s.p[8] = wf1; s.p[9] = wf2;
        castTall_kernel<<<4096, 256, 0, stream>>>(s, wqkv1t, wf1t, wf2t);
    }
    biaspack_kernel<<<20, 256, 0, stream>>>(bq1, bk1, bv1, bk2, bv2, bqkv1, bkv2);

    const int M = NB * SEQ;
    dim3 gQKV(3 * DM / 128, M / 128);
    dim3 gKV(2 * DM / 128, M / 128);
    dim3 gDD64(DM / 128, M / 64);
    dim3 gDF(DFFN / 128, M / 128);
    dim3 gF2(DM / 128, M / 128, 2);

    // ---- MHA1 (self, causal) ----
    gemm_kernel<128, 128, 32, 1, 0, 1, 0, 1><<<gQKV, 256, 0, stream>>>(xb, wqkv1t, bqkv1, qkv1b, nullptr, nullptr, v1t, 2048, M, 3 * DM, DM);
    attn_kernel<1><<<2048, 256, 0, stream>>>(qkv1b, 3 * DM, qkv1b + DM, 3 * DM, v1t, nullptr, aw1, ctx);
    gemm_kernel<64, 128, 64, 1, 0, 0, 1, 0><<<gDD64, 256, 0, stream>>>(ctx, wo1t, bo1, nullptr, goutf, nullptr, nullptr, 0, M, DM, DM);
    ln_kernel<1, 0, 0><<<M, 256, 0, stream>>>(goutf, nullptr, x, g1, be1, out1f, out1b);

    // ---- MHA2 (cross, padding mask) ----
    gemm_kernel<64, 128, 64, 1, 0, 1, 0, 0><<<gDD64, 256, 0, stream>>>(out1b, wq2t, bq2, qb, nullptr, nullptr, nullptr, 0, M, DM, DM);
    gemm_kernel<128, 128, 32, 1, 0, 1, 0, 1><<<gKV, 256, 0, stream>>>(encb, wkv2t, bkv2, kv2b, nullptr, nullptr, v2t, 1024, M, 2 * DM, DM);
    attn_kernel<0><<<2048, 256, 0, stream>>>(qb, DM, kv2b, 2 * DM, v2t, pad, aw2, ctx);
    gemm_kernel<64, 128, 64, 1, 0, 0, 1, 0><<<gDD64, 256, 0, stream>>>(ctx, wo2t, bo2, nullptr, goutf, nullptr, nullptr, 0, M, DM, DM);
    ln_kernel<1, 0, 0><<<M, 256, 0, stream>>>(goutf, nullptr, out1f, g2, be2, out2f, out2b);

    // ---- FFN ----
    gemm_kernel<128, 128, 32, 1, 1, 1, 0, 0><<<gDF, 256, 0, stream>>>(out2b, wf1t, bf1, ffn1b, nullptr, nullptr, nullptr, 0, M, DFFN, DM);
    gemm_kernel<128, 128, 32, 2, 0, 0, 1, 0><<<gF2, 256, 0, stream>>>(ffn1b, wf2t, bf2, nullptr, goutf, gout2f, nullptr, 0, M, DM, DFFN);
    ln_kernel<0, 1, 1><<<M, 256, 0, stream>>>(goutf, gout2f, out2f, g3, be3, out3, nullptr);
}

// Round 11
// 494.101 us; speedup vs baseline: 1.1951x; 1.0022x over previous
//
#include <hip/hip_runtime.h>

#define NB 4
#define SEQ 1024
#define DM 1024
#define NH 16
#define DEP 64
#define DFFN 4096

typedef __attribute__((ext_vector_type(8))) short short8;
typedef __attribute__((ext_vector_type(4))) float f32x4;
typedef __attribute__((ext_vector_type(4))) unsigned short us4;

__device__ __forceinline__ unsigned short f2bf(float f) {
    union { float f; unsigned int u; } v; v.f = f;
    unsigned int u = v.u;
    return (unsigned short)((u + 0x7FFFu + ((u >> 16) & 1u)) >> 16);
}

__device__ __forceinline__ void gload16(const void* g, void* l) {
    __builtin_amdgcn_global_load_lds((const __attribute__((address_space(1))) unsigned int*)g,
                                     (__attribute__((address_space(3))) unsigned int*)l, 16, 0, 0);
}

// ---------------- dual cast f32 -> bf16 (NT loads) ----------------
__global__ __launch_bounds__(256) void cast2_kernel(const float* __restrict__ a,
                                                    const float* __restrict__ b,
                                                    unsigned short* __restrict__ oa,
                                                    unsigned short* __restrict__ ob, int n4) {
    int i = blockIdx.x * 256 + threadIdx.x;
    const float* in = blockIdx.y ? b : a;
    unsigned short* out = blockIdx.y ? ob : oa;
    if (i < n4) {
        f32x4 f = __builtin_nontemporal_load((const f32x4*)in + i);
        us4 u;
        u[0] = f2bf(f[0]); u[1] = f2bf(f[1]); u[2] = f2bf(f[2]); u[3] = f2bf(f[3]);
        ((us4*)out)[i] = u;
    }
}

// ---------------- batched transpose-cast: 8 squares + wf1 + wf2 ----------------
struct P10 { const float* p[10]; };
__global__ __launch_bounds__(256) void castTall_kernel(P10 s,
                                                       unsigned short* __restrict__ wsq,
                                                       unsigned short* __restrict__ wf1t,
                                                       unsigned short* __restrict__ wf2t) {
    __shared__ float tile[64][65];
    const int tid = blockIdx.x, t = threadIdx.x;
    const float* in; unsigned short* out; int R, C, r0, c0;
    if (tid < 2048) {
        int wi = tid >> 8, t2 = tid & 255;
        in = s.p[wi]; out = wsq + (size_t)wi * DM * DM; R = DM; C = DM;
        r0 = (t2 >> 4) * 64; c0 = (t2 & 15) * 64;
    } else if (tid < 3072) {
        int t2 = tid - 2048;
        in = s.p[8]; out = wf1t; R = DM; C = DFFN;
        r0 = (t2 >> 6) * 64; c0 = (t2 & 63) * 64;
    } else {
        int t2 = tid - 3072;
        in = s.p[9]; out = wf2t; R = DFFN; C = DM;
        r0 = (t2 >> 4) * 64; c0 = (t2 & 15) * 64;
    }
#pragma unroll
    for (int p = 0; p < 4; ++p) {
        int r = p * 16 + (t >> 4), c = (t & 15) * 4;
        f32x4 f = __builtin_nontemporal_load((const f32x4*)(in + (size_t)(r0 + r) * C + c0 + c));
        tile[r][c] = f[0]; tile[r][c + 1] = f[1]; tile[r][c + 2] = f[2]; tile[r][c + 3] = f[3];
    }
    __syncthreads();
#pragma unroll
    for (int p = 0; p < 4; ++p) {
        int n = p * 16 + (t >> 4), k = (t & 15) * 4;
        us4 u;
#pragma unroll
        for (int j = 0; j < 4; ++j) u[j] = f2bf(tile[k + j][n]);
        *(us4*)(out + (size_t)(c0 + n) * R + r0 + k) = u;
    }
}

// ---------------- bias concat pack ----------------
__global__ __launch_bounds__(256) void biaspack_kernel(const float* __restrict__ bq1,
                                                       const float* __restrict__ bk1,
                                                       const float* __restrict__ bv1,
                                                       const float* __restrict__ bk2,
                                                       const float* __restrict__ bv2,
                                                       float* __restrict__ bqkv1,
                                                       float* __restrict__ bkv2) {
    int i = blockIdx.x * 256 + threadIdx.x;
    if (i < 1024) bqkv1[i] = bq1[i];
    else if (i < 2048) bqkv1[i] = bk1[i - 1024];
    else if (i < 3072) bqkv1[i] = bv1[i - 2048];
    else if (i < 4096) bkv2[i - 3072] = bk2[i - 3072];
    else if (i < 5120) bkv2[i - 3072] = bv2[i - 4096];
}

// ---------------- bf16 GEMM: ring-3, counted vmcnt (T3/T4), BK64 bank-swizzle (T2), setprio (T5) ----------------
template <int BM, int BN, int BK, int KSPLIT, int RELU, int WB, int WF, int WVT>
__global__ __launch_bounds__(256) void gemm_kernel(const unsigned short* __restrict__ A,
                                                   const unsigned short* __restrict__ Wt,
                                                   const float* __restrict__ bias,
                                                   unsigned short* __restrict__ Cb,
                                                   float* __restrict__ Cf,
                                                   float* __restrict__ Cf2,
                                                   unsigned short* __restrict__ Vt,
                                                   int vstart,
                                                   int M, int N, int K) {
    constexpr int AM = BM / 32;
    constexpr int KS = BK / 32;
    constexpr int LPR = BK / 8;
    constexpr int RPI = 64 / LPR;
    constexpr int AR = (BM / 4) / RPI;
    constexpr int BR = (BN / 4) / RPI;
    constexpr int NLD = AR + BR;         // per-thread loads per staged tile
    __shared__ unsigned short As[3][BM * BK];
    __shared__ unsigned short Bs[3][BN * BK];
    const int t = threadIdx.x;
    const int lane = t & 63, w = t >> 6;
    const int nwg = gridDim.x * gridDim.y;
    const int rawid = blockIdx.y * gridDim.x + blockIdx.x;
    const int swz = (rawid & 7) * (nwg >> 3) + (rawid >> 3);
    const int m0 = (swz / gridDim.x) * BM, n0 = (swz % gridDim.x) * BN;
    const int wm = (w >> 1) * (BM / 2), wn = (w & 1) * (BN / 2);
    const int lr = lane & 15, g = lane >> 4, kb = g * 8;
    // staging: BK=64 gets the attn-verified source-side XOR involution (rule #21 pair with read XOR)
    const int srow = lane / LPR;
    const int sslotl = lane % LPR;
    const int sswz = (BK == 64) ? (sslotl ^ srow) : sslotl;
    const int scol = sswz * 8;
    const int kofs = (KSPLIT == 2 && blockIdx.z) ? K / 2 : 0;
    const int Keff = (KSPLIT == 2) ? K / 2 : K;
    const int nk = Keff / BK;

    f32x4 acc[AM][4];
#pragma unroll
    for (int a = 0; a < AM; ++a)
#pragma unroll
        for (int b = 0; b < 4; ++b)
#pragma unroll
            for (int j = 0; j < 4; ++j) acc[a][b][j] = 0.f;

    auto STAGE = [&](int buf, int kt) {
#pragma unroll
        for (int ia = 0; ia < AR; ++ia) {
            int rb = w * (BM / 4) + ia * RPI;
            gload16(A + (size_t)(m0 + rb + srow) * K + kt + scol, &As[buf][rb * BK]);
        }
#pragma unroll
        for (int ib = 0; ib < BR; ++ib) {
            int rb = w * (BN / 4) + ib * RPI;
            gload16(Wt + (size_t)(n0 + rb + srow) * K + kt + scol, &Bs[buf][rb * BK]);
        }
    };

    STAGE(0, kofs);
    if (nk > 1) STAGE(1, kofs + BK);
    int sb = 2, cb = 0;
    for (int i = 0; i < nk; ++i) {
        if (i + 2 < nk) {
            STAGE(sb, kofs + (i + 2) * BK);
            if (++sb == 3) sb = 0;
            asm volatile("s_waitcnt vmcnt(%0)" :: "n"(2 * NLD) : "memory");
        } else if (i + 1 < nk) {
            asm volatile("s_waitcnt vmcnt(%0)" :: "n"(NLD) : "memory");
        } else {
            asm volatile("s_waitcnt vmcnt(0)" ::: "memory");
        }
        __builtin_amdgcn_s_barrier();   // all waves' tile-i loads retired

        short8 af[AM][KS], bfr[4][KS];
#pragma unroll
        for (int ii = 0; ii < AM; ++ii)
#pragma unroll
            for (int ks = 0; ks < KS; ++ks) {
                int ofs = (BK == 64) ? (((ks * 4 + g) ^ (lr & 7)) << 3) : (ks * 32 + kb);
                af[ii][ks] = *(const short8*)&As[cb][(wm + ii * 16 + lr) * BK + ofs];
            }
#pragma unroll
        for (int ii = 0; ii < 4; ++ii)
#pragma unroll
            for (int ks = 0; ks < KS; ++ks) {
                int ofs = (BK == 64) ? (((ks * 4 + g) ^ (lr & 7)) << 3) : (ks * 32 + kb);
                bfr[ii][ks] = *(const short8*)&Bs[cb][(wn + ii * 16 + lr) * BK + ofs];
            }
        __builtin_amdgcn_s_setprio(1);
#pragma unroll
        for (int ks = 0; ks < KS; ++ks)
#pragma unroll
            for (int am = 0; am < AM; ++am)
#pragma unroll
                for (int bn = 0; bn < 4; ++bn)
                    acc[am][bn] = __builtin_amdgcn_mfma_f32_16x16x32_bf16(af[am][ks], bfr[bn][ks], acc[am][bn], 0, 0, 0);
        __builtin_amdgcn_s_setprio(0);
        if (++cb == 3) cb = 0;
        __builtin_amdgcn_s_barrier();   // reads done before this buf is re-staged
    }

    float* cfo = (KSPLIT == 2 && blockIdx.z) ? Cf2 : Cf;
    const bool addb = bias && (KSPLIT == 1 || blockIdx.z == 0);
#pragma unroll
    for (int am = 0; am < AM; ++am) {
#pragma unroll
        for (int bn = 0; bn < 4; ++bn) {
            int col = n0 + wn + bn * 16 + lr;
            float bv = addb ? bias[col] : 0.f;
            int rowb = m0 + wm + am * 16 + g * 4;
            float vv[4];
#pragma unroll
            for (int i = 0; i < 4; ++i) {
                float v = acc[am][bn][i] + bv;
                if (RELU) v = v > 0.f ? v : 0.f;
                vv[i] = v;
                if (WF) cfo[(size_t)(rowb + i) * N + col] = v;
                if (WB) Cb[(size_t)(rowb + i) * N + col] = f2bf(v);
            }
            if (WVT && col >= vstart) {
                int h = (col - vstart) >> 6, dep = (col - vstart) & 63;
                int b = rowb >> 10, kpos = rowb & 1023;
                us4 u;
#pragma unroll
                for (int i = 0; i < 4; ++i) u[i] = f2bf(vv[i]);
                *(us4*)(Vt + ((size_t)(b * NH + h) * DEP + dep) * SEQ + kpos) = u;
            }
        }
    }
}

// ---------------- fused attention v6: barrier-free ring-3 QK pipeline; setprio; NT aw last ----------------
template <int CAUSAL>
__global__ __launch_bounds__(256, 2) void attn_kernel(const unsigned short* __restrict__ Q, int ldq,
                                                      const unsigned short* __restrict__ Kp, int ldk,
                                                      const unsigned short* __restrict__ Vt,
                                                      const float* __restrict__ pad,
                                                      float* __restrict__ aw,
                                                      unsigned short* __restrict__ ctx) {
    __shared__ unsigned short Ks[3][128 * 64];  // 48 KB ring, source-swizzled
    __shared__ unsigned short Pch[32 * 128];    // 8 KB, 16B-XOR swizzled
    __shared__ float redm[4][32];
    __shared__ float reds[4][32];
    const int t = threadIdx.x, lane = t & 63, w = t >> 6;
    const int lr = lane & 15, g = lane >> 4;
    const int id = blockIdx.x;
    const int bh = (id & 7) + ((id >> 8) << 3);
    const int qt = (id >> 3) & 31;
    const int q0 = qt * 32;
    const int b = bh >> 4, h = bh & 15;
    const size_t qbase = (size_t)b * SEQ * ldq + (size_t)h * DEP;
    const size_t kbase = (size_t)b * SEQ * ldk + (size_t)h * DEP;
    const int cmax = CAUSAL ? (q0 >> 7) + 1 : 8;

    const int srow = lane >> 3;
    const int sslot = (lane & 7) ^ srow;

    short8 aq[2][2];
#pragma unroll
    for (int p = 0; p < 2; ++p)
#pragma unroll
        for (int ks = 0; ks < 2; ++ks)
            aq[p][ks] = *(const short8*)(Q + qbase + (size_t)(q0 + p * 16 + lr) * ldq + ks * 32 + g * 8);

    f32x4 acc[2][8][2];
#pragma unroll
    for (int p = 0; p < 2; ++p)
#pragma unroll
        for (int c = 0; c < 8; ++c)
#pragma unroll
            for (int bn = 0; bn < 2; ++bn)
#pragma unroll
                for (int j = 0; j < 4; ++j) acc[p][c][bn][j] = 0.f;

#define STAGE_K(BUF, CH)                                                                   \
    {                                                                                      \
        _Pragma("unroll") for (int i_ = 0; i_ < 4; ++i_) {                                 \
            int rb_ = w * 32 + i_ * 8;                                                     \
            gload16(Kp + kbase + (size_t)((CH) * 128 + rb_ + srow) * ldk + sslot * 8,      \
                    &Ks[BUF][rb_ * 64]);                                                   \
        }                                                                                  \
    }

    // ---- QK^T: barrier-free per-wave pipeline (2-deep prefetch) ----
    STAGE_K(0, 0);
    if (1 < cmax) STAGE_K(1, 1);
#pragma unroll
    for (int c = 0; c < 8; ++c) {
        if (c < cmax) {
            if (c + 2 < cmax) {
                STAGE_K((c + 2) % 3, c + 2);
                asm volatile("s_waitcnt vmcnt(8)" ::: "memory");
            } else if (c + 1 < cmax) {
                asm volatile("s_waitcnt vmcnt(4)" ::: "memory");
            } else {
                asm volatile("s_waitcnt vmcnt(0)" ::: "memory");
            }
            __builtin_amdgcn_s_setprio(1);
#pragma unroll
            for (int ks = 0; ks < 2; ++ks)
#pragma unroll
                for (int bn = 0; bn < 2; ++bn) {
                    int row = w * 32 + bn * 16 + lr;
                    short8 bk = *(const short8*)((const char*)&Ks[c % 3][0] + row * 128 +
                                                 ((ks * 64 + g * 16) ^ ((lr & 7) << 4)));
                    acc[0][c][bn] = __builtin_amdgcn_mfma_f32_16x16x32_bf16(bk, aq[0][ks], acc[0][c][bn], 0, 0, 0);
                    acc[1][c][bn] = __builtin_amdgcn_mfma_f32_16x16x32_bf16(bk, aq[1][ks], acc[1][c][bn], 0, 0, 0);
                }
            __builtin_amdgcn_s_setprio(0);
        }
    }
#undef STAGE_K

    // ---- scale + masks + row max ----
    float mrow[2] = {-1e30f, -1e30f};
#pragma unroll
    for (int c = 0; c < 8; ++c) {
        if (c < cmax) {
#pragma unroll
            for (int bn = 0; bn < 2; ++bn) {
                int k4 = c * 128 + w * 32 + bn * 16 + g * 4;
                f32x4 pv = {0.f, 0.f, 0.f, 0.f};
                if (pad) pv = *(const f32x4*)(pad + (size_t)b * SEQ + k4);
#pragma unroll
                for (int p = 0; p < 2; ++p) {
                    int q = q0 + p * 16 + lr;
#pragma unroll
                    for (int i = 0; i < 4; ++i) {
                        float v = acc[p][c][bn][i] * 0.125f + pv[i] * -1e9f;
                        if (CAUSAL && (k4 + i) > q) v = -1e30f;
                        acc[p][c][bn][i] = v;
                        mrow[p] = fmaxf(mrow[p], v);
                    }
                }
            }
        }
    }
#pragma unroll
    for (int p = 0; p < 2; ++p) {
        mrow[p] = fmaxf(mrow[p], __shfl_xor(mrow[p], 16));
        mrow[p] = fmaxf(mrow[p], __shfl_xor(mrow[p], 32));
    }
    if (lane < 16) { redm[w][lr] = mrow[0]; redm[w][16 + lr] = mrow[1]; }
    __syncthreads();
    float Mv[2];
#pragma unroll
    for (int p = 0; p < 2; ++p)
        Mv[p] = fmaxf(fmaxf(redm[0][p * 16 + lr], redm[1][p * 16 + lr]),
                      fmaxf(redm[2][p * 16 + lr], redm[3][p * 16 + lr]));

    // ---- exp + row sum ----
    float srw[2] = {0.f, 0.f};
#pragma unroll
    for (int c = 0; c < 8; ++c) {
        if (c < cmax) {
#pragma unroll
            for (int p = 0; p < 2; ++p)
#pragma unroll
                for (int bn = 0; bn < 2; ++bn)
#pragma unroll
                    for (int i = 0; i < 4; ++i) {
                        float e = __expf(acc[p][c][bn][i] - Mv[p]);
                        acc[p][c][bn][i] = e;
                        srw[p] += e;
                    }
        }
    }
#pragma unroll
    for (int p = 0; p < 2; ++p) {
        srw[p] += __shfl_xor(srw[p], 16);
        srw[p] += __shfl_xor(srw[p], 32);
    }
    if (lane < 16) { reds[w][lr] = srw[0]; reds[w][16 + lr] = srw[1]; }
    __syncthreads();
    float inv[2];
#pragma unroll
    for (int p = 0; p < 2; ++p)
        inv[p] = 1.0f / (reds[0][p * 16 + lr] + reds[1][p * 16 + lr] +
                         reds[2][p * 16 + lr] + reds[3][p * 16 + lr]);

    // ---- PV (cross-wave Pch -> barriers stay) ----
    f32x4 acc2[2];
#pragma unroll
    for (int p = 0; p < 2; ++p)
#pragma unroll
        for (int j = 0; j < 4; ++j) acc2[p][j] = 0.f;
    char* pch = (char*)Pch;
    const int sw = (lr & 7) << 4;
#pragma unroll
    for (int c = 0; c < 8; ++c) {
        if (c < cmax) {
            __syncthreads();
#pragma unroll
            for (int p = 0; p < 2; ++p)
#pragma unroll
                for (int bn = 0; bn < 2; ++bn) {
                    us4 u;
#pragma unroll
                    for (int i = 0; i < 4; ++i) u[i] = f2bf(acc[p][c][bn][i] * inv[p]);
                    *(us4*)(pch + (p * 16 + lr) * 256 + ((w * 64 + bn * 32 + g * 8) ^ sw)) = u;
                }
            __syncthreads();
            __builtin_amdgcn_s_setprio(1);
#pragma unroll
            for (int ks = 0; ks < 4; ++ks) {
                short8 bf = *(const short8*)(Vt + ((size_t)bh * DEP + w * 16 + lr) * SEQ + c * 128 + ks * 32 + g * 8);
#pragma unroll
                for (int p = 0; p < 2; ++p) {
                    short8 af = *(const short8*)(pch + (p * 16 + lr) * 256 + ((ks * 64 + g * 16) ^ sw));
                    acc2[p] = __builtin_amdgcn_mfma_f32_16x16x32_bf16(af, bf, acc2[p], 0, 0, 0);
                }
            }
            __builtin_amdgcn_s_setprio(0);
        }
    }
#pragma unroll
    for (int p = 0; p < 2; ++p)
#pragma unroll
        for (int i = 0; i < 4; ++i)
            ctx[((size_t)b * SEQ + q0 + p * 16 + g * 4 + i) * DM + h * DEP + w * 16 + lr] = f2bf(acc2[p][i]);

    // ---- aw writes LAST, non-temporal ----
#pragma unroll
    for (int p = 0; p < 2; ++p) {
        float* awrow = aw + ((size_t)bh * SEQ + q0 + p * 16 + lr) * SEQ;
#pragma unroll
        for (int c = 0; c < 8; ++c)
#pragma unroll
            for (int bn = 0; bn < 2; ++bn) {
                f32x4 o = {0.f, 0.f, 0.f, 0.f};
                if (c < cmax) {
#pragma unroll
                    for (int i = 0; i < 4; ++i) o[i] = acc[p][c][bn][i] * inv[p];
                }
                __builtin_nontemporal_store(o, (f32x4*)(awrow + c * 128 + w * 32 + bn * 16 + g * 4));
            }
    }
}

// ---------------- residual + layernorm: out = LN(X [+ X2] + R) ----------------
template <int WB, int X2EN, int NTF>
__global__ __launch_bounds__(256) void ln_kernel(const float* __restrict__ X,
                                                 const float* __restrict__ X2,
                                                 const float* __restrict__ R,
                                                 const float* __restrict__ gamma,
                                                 const float* __restrict__ beta,
                                                 float* __restrict__ outF,
                                                 unsigned short* __restrict__ outB) {
    size_t row = blockIdx.x;
    const int t = threadIdx.x;
    float4 a = ((const float4*)(X + (row << 10)))[t];
    float4 r = ((const float4*)(R + (row << 10)))[t];
    float v0 = a.x + r.x, v1 = a.y + r.y, v2 = a.z + r.z, v3 = a.w + r.w;
    if (X2EN) {
        float4 a2 = ((const float4*)(X2 + (row << 10)))[t];
        v0 += a2.x; v1 += a2.y; v2 += a2.z; v3 += a2.w;
    }
    float s = v0 + v1 + v2 + v3;
    float q = v0 * v0 + v1 * v1 + v2 * v2 + v3 * v3;
#pragma unroll
    for (int off = 32; off; off >>= 1) {
        s += __shfl_down(s, off);
        q += __shfl_down(q, off);
    }
    __shared__ float rs[4], rq[4];
    if ((t & 63) == 0) { rs[t >> 6] = s; rq[t >> 6] = q; }
    __syncthreads();
    s = rs[0] + rs[1] + rs[2] + rs[3];
    q = rq[0] + rq[1] + rq[2] + rq[3];
    float mean = s * (1.0f / 1024.0f);
    float var = q * (1.0f / 1024.0f) - mean * mean;
    float inv = rsqrtf(var + 1e-6f);
    float g0 = gamma[t * 4], g1 = gamma[t * 4 + 1], g2 = gamma[t * 4 + 2], g3 = gamma[t * 4 + 3];
    float b0 = beta[t * 4], b1 = beta[t * 4 + 1], b2 = beta[t * 4 + 2], b3 = beta[t * 4 + 3];
    f32x4 o;
    o[0] = (v0 - mean) * inv * g0 + b0;
    o[1] = (v1 - mean) * inv * g1 + b1;
    o[2] = (v2 - mean) * inv * g2 + b2;
    o[3] = (v3 - mean) * inv * g3 + b3;
    if (NTF) __builtin_nontemporal_store(o, (f32x4*)(outF + (row << 10)) + t);
    else ((f32x4*)(outF + (row << 10)))[t] = o;
    if (WB) {
        us4 u;
        u[0] = f2bf(o[0]); u[1] = f2bf(o[1]); u[2] = f2bf(o[2]); u[3] = f2bf(o[3]);
        ((us4*)(outB + (row << 10)))[t] = u;
    }
}

extern "C" void kernel_launch(void* const* d_in, const int* in_sizes, int n_in,
                              void* d_out, int out_size, void* d_ws, size_t ws_size,
                              hipStream_t stream) {
    const float* x = (const float*)d_in[0];
    const float* enc = (const float*)d_in[1];
    const float* pad = (const float*)d_in[3];
    const float* wq1 = (const float*)d_in[4];  const float* bq1 = (const float*)d_in[5];
    const float* wk1 = (const float*)d_in[6];  const float* bk1 = (const float*)d_in[7];
    const float* wv1 = (const float*)d_in[8];  const float* bv1 = (const float*)d_in[9];
    const float* wo1 = (const float*)d_in[10]; const float* bo1 = (const float*)d_in[11];
    const float* wq2 = (const float*)d_in[12]; const float* bq2 = (const float*)d_in[13];
    const float* wk2 = (const float*)d_in[14]; const float* bk2 = (const float*)d_in[15];
    const float* wv2 = (const float*)d_in[16]; const float* bv2 = (const float*)d_in[17];
    const float* wo2 = (const float*)d_in[18]; const float* bo2 = (const float*)d_in[19];
    const float* wf1 = (const float*)d_in[20]; const float* bf1 = (const float*)d_in[21];
    const float* wf2 = (const float*)d_in[22]; const float* bf2 = (const float*)d_in[23];
    const float* g1 = (const float*)d_in[24]; const float* be1 = (const float*)d_in[25];
    const float* g2 = (const float*)d_in[26]; const float* be2 = (const float*)d_in[27];
    const float* g3 = (const float*)d_in[28]; const float* be3 = (const float*)d_in[29];

    float* out3 = (float*)d_out;
    float* aw1 = out3 + (size_t)NB * SEQ * DM;
    float* aw2 = aw1 + (size_t)NB * NH * SEQ * SEQ;

    char* ws = (char*)d_ws;
    size_t off = 0;
    auto take = [&](size_t n) { char* p = ws + off; off += (n + 255) & ~(size_t)255; return p; };
    const size_t SZ_SD_BF = (size_t)NB * SEQ * DM * 2;
    const size_t SZ_SD_F  = (size_t)NB * SEQ * DM * 4;
    const size_t SZ_DD_BF = (size_t)DM * DM * 2;

    unsigned short* wqkv1t = (unsigned short*)take(3 * SZ_DD_BF);
    unsigned short* wq2t   = (unsigned short*)take(SZ_DD_BF);
    unsigned short* wkv2t  = (unsigned short*)take(2 * SZ_DD_BF);
    unsigned short* wo1t   = (unsigned short*)take(SZ_DD_BF);
    unsigned short* wo2t   = (unsigned short*)take(SZ_DD_BF);
    unsigned short* wf1t   = (unsigned short*)take((size_t)DM * DFFN * 2);
    unsigned short* wf2t   = (unsigned short*)take((size_t)DFFN * DM * 2);
    float* bqkv1 = (float*)take(3 * DM * 4);
    float* bkv2  = (float*)take(2 * DM * 4);
    unsigned short* xb    = (unsigned short*)take(SZ_SD_BF);
    unsigned short* encb  = (unsigned short*)take(SZ_SD_BF);
    unsigned short* qkv1b = (unsigned short*)take(3 * SZ_SD_BF);
    unsigned short* v1t   = (unsigned short*)take(SZ_SD_BF);
    unsigned short* qb    = (unsigned short*)take(SZ_SD_BF);
    unsigned short* kv2b  = (unsigned short*)take(2 * SZ_SD_BF);
    unsigned short* v2t   = (unsigned short*)take(SZ_SD_BF);
    unsigned short* ctx   = (unsigned short*)take(SZ_SD_BF);
    float* goutf  = (float*)take(SZ_SD_F);
    float* out1f  = (float*)take(SZ_SD_F);
    unsigned short* out1b = (unsigned short*)take(SZ_SD_BF);
    float* out2f  = (float*)take(SZ_SD_F);
    unsigned short* out2b = (unsigned short*)take(SZ_SD_BF);
    unsigned short* ffn1b = (unsigned short*)take((size_t)NB * SEQ * DFFN * 2);

    // ----- prep: 3 launches -----
    {
        int n4 = NB * SEQ * DM / 4;
        dim3 gc((n4 + 255) / 256, 2);
        cast2_kernel<<<gc, 256, 0, stream>>>(x, enc, xb, encb, n4);
    }
    {
        P10 s;
        s.p[0] = wq1; s.p[1] = wk1; s.p[2] = wv1; s.p[3] = wq2;
        s.p[4] = wk2; s.p[5] = wv2; s.p[6] = wo1; s.p[7] = wo2;
        s.p[8] = wf1; s.p[9] = wf2;
        castTall_kernel<<<4096, 256, 0, stream>>>(s, wqkv1t, wf1t, wf2t);
    }
    biaspack_kernel<<<20, 256, 0, stream>>>(bq1, bk1, bv1, bk2, bv2, bqkv1, bkv2);

    const int M = NB * SEQ;
    dim3 gQKV(3 * DM / 128, M / 128);
    dim3 gKV(2 * DM / 128, M / 128);
    dim3 gDD64(DM / 128, M / 64);
    dim3 gDF(DFFN / 128, M / 128);

    // ---- MHA1 (self, causal) ----
    gemm_kernel<128, 128, 32, 1, 0, 1, 0, 1><<<gQKV, 256, 0, stream>>>(xb, wqkv1t, bqkv1, qkv1b, nullptr, nullptr, v1t, 2048, M, 3 * DM, DM);
    attn_kernel<1><<<2048, 256, 0, stream>>>(qkv1b, 3 * DM, qkv1b + DM, 3 * DM, v1t, nullptr, aw1, ctx);
    gemm_kernel<64, 128, 64, 1, 0, 0, 1, 0><<<gDD64, 256, 0, stream>>>(ctx, wo1t, bo1, nullptr, goutf, nullptr, nullptr, 0, M, DM, DM);
    ln_kernel<1, 0, 0><<<M, 256, 0, stream>>>(goutf, nullptr, x, g1, be1, out1f, out1b);

    // ---- MHA2 (cross, padding mask) ----
    gemm_kernel<64, 128, 64, 1, 0, 1, 0, 0><<<gDD64, 256, 0, stream>>>(out1b, wq2t, bq2, qb, nullptr, nullptr, nullptr, 0, M, DM, DM);
    gemm_kernel<128, 128, 32, 1, 0, 1, 0, 1><<<gKV, 256, 0, stream>>>(encb, wkv2t, bkv2, kv2b, nullptr, nullptr, v2t, 1024, M, 2 * DM, DM);
    attn_kernel<0><<<2048, 256, 0, stream>>>(qb, DM, kv2b, 2 * DM, v2t, pad, aw2, ctx);
    gemm_kernel<64, 128, 64, 1, 0, 0, 1, 0><<<gDD64, 256, 0, stream>>>(ctx, wo2t, bo2, nullptr, goutf, nullptr, nullptr, 0, M, DM, DM);
    ln_kernel<1, 0, 0><<<M, 256, 0, stream>>>(goutf, nullptr, out1f, g2, be2, out2f, out2b);

    // ---- FFN ----
    gemm_kernel<128, 128, 32, 1, 1, 1, 0, 0><<<gDF, 256, 0, stream>>>(out2b, wf1t, bf1, ffn1b, nullptr, nullptr, nullptr, 0, M, DFFN, DM);
    gemm_kernel<64, 128, 64, 1, 0, 0, 1, 0><<<gDD64, 256, 0, stream>>>(ffn1b, wf2t, bf2, nullptr, goutf, nullptr, nullptr, 0, M, DM, DFFN);
    ln_kernel<0, 0, 1><<<M, 256, 0, stream>>>(goutf, nullptr, out2f, g3, be3, out3, nullptr);
}